// Round 1
// baseline (58874.072 us; speedup 1.0000x reference)
//
#include <hip/hip_runtime.h>
#include <cstdint>
#include <cstddef>

// ConvGRU autoencoder, fp32 baseline.
// Key observation: spatial width == 1 with SAME padding -> 3x3 conv degenerates
// to a 1-D 3-tap conv along F using only kernel column kw==1.
// Encoder (e0->e1) fused in one kernel (layer output == hidden state, stays in LDS).
// Decoder (d0->d1->1x1 conv) fused in another. Only y1 (T,B,64,F) hits global.
// One block per batch item, 512 threads, states in LDS.

#define F_ 128
#define FP_ 130   // padded row stride (1 zero on each side for the 3-tap halo)
#define T_ 100
#define B_ 64

__device__ __forceinline__ float sigm(float x) { return 1.0f / (1.0f + expf(-x)); }

// Accumulate a 3-tap conv over NR input rows (LDS, padded stride FP_) into
// acc[PG] outputs (co = co0 .. co0+PG-1), weights wT layout [(ci*3+k)*CO + co].
template <int NR, int CO, int PG>
__device__ __forceinline__ void conv_all(float* __restrict__ acc,
                                         const float* __restrict__ rows, int p,
                                         const float* __restrict__ wT,
                                         int co0, int ciBase) {
  const float* r = rows;
  const float* wp = wT + (size_t)(ciBase * 3) * CO + co0;
#pragma unroll 2
  for (int ci = 0; ci < NR; ++ci) {
    const float am = r[p - 1];
    const float a0 = r[p];
    const float ap = r[p + 1];
#pragma unroll
    for (int k = 0; k < 3; ++k) {
      const float a = (k == 0) ? am : ((k == 1) ? a0 : ap);
      const float* wk = wp + k * CO;
#pragma unroll
      for (int j4 = 0; j4 < PG; j4 += 4) {
        const float4 w = *(const float4*)(wk + j4);
        acc[j4 + 0] = fmaf(w.x, a, acc[j4 + 0]);
        acc[j4 + 1] = fmaf(w.y, a, acc[j4 + 1]);
        acc[j4 + 2] = fmaf(w.z, a, acc[j4 + 2]);
        acc[j4 + 3] = fmaf(w.w, a, acc[j4 + 3]);
      }
    }
    r += FP_;
    wp += 3 * CO;
  }
}

// One ConvGRU step. xin: CIN rows in LDS, h: H rows in LDS (updated in place).
// rh, ub: LDS scratch (>= H rows each). 512 threads: f = tid&127, g = tid>>7.
template <int CIN, int H>
__device__ void gru_step(int tid, const float* __restrict__ xin,
                         float* __restrict__ h, float* __restrict__ rh,
                         float* __restrict__ ub,
                         const float* __restrict__ wgT, const float* __restrict__ bg,
                         const float* __restrict__ wcT, const float* __restrict__ bc) {
  const int f = tid & (F_ - 1);
  const int g = tid >> 7;
  const int p = f + 1;

  // ---- phase A: gates g = conv([x;h], wg)+bg ; r,u = sigmoid(split(g)) ----
  {
    constexpr int CO = 2 * H;
    constexpr int PG = CO / 4;  // 16 or 32 outputs per thread
    const int co0 = g * PG;
    float acc[PG];
#pragma unroll
    for (int j = 0; j < PG; ++j) acc[j] = bg[co0 + j];
    conv_all<CIN, CO, PG>(acc, xin, p, wgT, co0, 0);
    conv_all<H, CO, PG>(acc, h, p, wgT, co0, CIN);
    if (co0 < H) {  // r-half: store r*h   (co0 is a multiple of PG; H % PG == 0)
#pragma unroll
      for (int j = 0; j < PG; ++j) {
        const int co = co0 + j;
        rh[co * FP_ + p] = sigm(acc[j]) * h[co * FP_ + p];
      }
    } else {  // u-half
#pragma unroll
      for (int j = 0; j < PG; ++j) {
        const int co = co0 + j - H;
        ub[co * FP_ + p] = sigm(acc[j]);
      }
    }
  }
  __syncthreads();

  // ---- phase B: c = tanh(conv([x; r*h], wc)+bc) ; h = (1-u)h + u c ----
  {
    constexpr int CO = H;
    constexpr int PG = CO / 4;  // 8 or 16
    const int co0 = g * PG;
    float acc[PG];
#pragma unroll
    for (int j = 0; j < PG; ++j) acc[j] = bc[co0 + j];
    conv_all<CIN, CO, PG>(acc, xin, p, wcT, co0, 0);
    conv_all<H, CO, PG>(acc, rh, p, wcT, co0, CIN);
#pragma unroll
    for (int j = 0; j < PG; ++j) {
      const int co = co0 + j;
      const float c = tanhf(acc[j]);
      const float uu = ub[co * FP_ + p];
      const float hp = h[co * FP_ + p];
      h[co * FP_ + p] = fmaf(uu, c - hp, hp);  // (1-u)h + u c
    }
  }
  __syncthreads();
}

// ---------------- encoder: e0 (1->32), e1 (32->64), emit y1 sequence ----------
__global__ __launch_bounds__(512, 1) void enc_kernel(
    const float* __restrict__ x,
    const float* __restrict__ wgT0, const float* __restrict__ bg0,
    const float* __restrict__ wcT0, const float* __restrict__ bc0,
    const float* __restrict__ wgT1, const float* __restrict__ bg1,
    const float* __restrict__ wcT1, const float* __restrict__ bc1,
    float* __restrict__ y1g, float* __restrict__ h0f) {
  extern __shared__ float smem[];
  float* xbuf = smem;            // FP_
  float* h0 = xbuf + FP_;        // 32*FP_
  float* h1 = h0 + 32 * FP_;     // 64*FP_
  float* rh = h1 + 64 * FP_;     // 64*FP_
  float* ub = rh + 64 * FP_;     // 64*FP_  -> total 225*FP_ floats
  const int tid = threadIdx.x;
  const int b = blockIdx.x;

  for (int i = tid; i < 225 * FP_; i += 512) smem[i] = 0.0f;
  __syncthreads();

  for (int t = 0; t < T_; ++t) {
    if (tid < F_) xbuf[1 + tid] = x[((size_t)b * T_ + t) * F_ + tid];
    __syncthreads();
    gru_step<1, 32>(tid, xbuf, h0, rh, ub, wgT0, bg0, wcT0, bc0);
    gru_step<32, 64>(tid, h0, h1, rh, ub, wgT1, bg1, wcT1, bc1);
    float* dst = y1g + ((size_t)b * T_ + t) * 64 * F_;
    for (int i = tid; i < 64 * F_; i += 512)
      dst[i] = h1[(i >> 7) * FP_ + 1 + (i & (F_ - 1))];
  }
  __syncthreads();
  for (int i = tid; i < 32 * F_; i += 512)
    h0f[(size_t)b * 32 * F_ + i] = h0[(i >> 7) * FP_ + 1 + (i & (F_ - 1))];
}

// --------- decoder: d0 (64->64), d1 (64->32), fused 1x1 conv to output --------
__global__ __launch_bounds__(512, 1) void dec_kernel(
    const float* __restrict__ y1g, const float* __restrict__ h0f,
    const float* __restrict__ wgT0, const float* __restrict__ bg0,
    const float* __restrict__ wcT0, const float* __restrict__ bc0,
    const float* __restrict__ wgT1, const float* __restrict__ bg1,
    const float* __restrict__ wcT1, const float* __restrict__ bc1,
    const float* __restrict__ fw, const float* __restrict__ fb,
    float* __restrict__ out) {
  extern __shared__ float smem[];
  float* y1t = smem;             // 64*FP_
  float* hd0 = y1t + 64 * FP_;   // 64*FP_
  float* hd1 = hd0 + 64 * FP_;   // 32*FP_
  float* rh = hd1 + 32 * FP_;    // 64*FP_
  float* ub = rh + 64 * FP_;     // 64*FP_  -> total 288*FP_ floats
  const int tid = threadIdx.x;
  const int b = blockIdx.x;

  for (int i = tid; i < 288 * FP_; i += 512) smem[i] = 0.0f;
  __syncthreads();

  {  // init states: hd0 = h1_final = y1[t=99]; hd1 = h0_final
    const float* s1 = y1g + ((size_t)b * T_ + (T_ - 1)) * 64 * F_;
    for (int i = tid; i < 64 * F_; i += 512)
      hd0[(i >> 7) * FP_ + 1 + (i & (F_ - 1))] = s1[i];
    const float* s2 = h0f + (size_t)b * 32 * F_;
    for (int i = tid; i < 32 * F_; i += 512)
      hd1[(i >> 7) * FP_ + 1 + (i & (F_ - 1))] = s2[i];
  }
  __syncthreads();

  for (int t = 0; t < T_; ++t) {
    const float* src = y1g + ((size_t)b * T_ + t) * 64 * F_;
    for (int i = tid; i < 64 * F_; i += 512)
      y1t[(i >> 7) * FP_ + 1 + (i & (F_ - 1))] = src[i];
    __syncthreads();
    gru_step<64, 64>(tid, y1t, hd0, rh, ub, wgT0, bg0, wcT0, bc0);
    gru_step<64, 32>(tid, hd0, hd1, rh, ub, wgT1, bg1, wcT1, bc1);
    if (tid < F_) {  // final 1x1 conv over 32 channels
      float a = fb[0];
#pragma unroll
      for (int c = 0; c < 32; ++c) a = fmaf(fw[c], hd1[c * FP_ + 1 + tid], a);
      out[((size_t)b * T_ + t) * F_ + tid] = a;
    }
  }
}

// Repack conv weight (CO,CI,3,3) -> wT[(ci*3+k)*CO + co] using only kw==1 column.
__global__ void repack_kernel(const float* __restrict__ src, float* __restrict__ dst,
                              int CO, int CI) {
  const int n = CO * CI * 3;
  for (int i = blockIdx.x * blockDim.x + threadIdx.x; i < n;
       i += gridDim.x * blockDim.x) {
    const int co = i / (CI * 3);
    const int rem = i - co * (CI * 3);
    const int ci = rem / 3;
    const int k = rem - ci * 3;
    dst[(size_t)(ci * 3 + k) * CO + co] = src[((size_t)(co * CI + ci) * 3 + k) * 3 + 1];
  }
}

extern "C" void kernel_launch(void* const* d_in, const int* in_sizes, int n_in,
                              void* d_out, int out_size, void* d_ws, size_t ws_size,
                              hipStream_t stream) {
  (void)in_sizes; (void)n_in; (void)out_size; (void)ws_size;
  const float* x     = (const float*)d_in[0];
  const float* e0_wg = (const float*)d_in[1];
  const float* e0_bg = (const float*)d_in[2];
  const float* e0_wc = (const float*)d_in[3];
  const float* e0_bc = (const float*)d_in[4];
  const float* e1_wg = (const float*)d_in[5];
  const float* e1_bg = (const float*)d_in[6];
  const float* e1_wc = (const float*)d_in[7];
  const float* e1_bc = (const float*)d_in[8];
  const float* d0_wg = (const float*)d_in[9];
  const float* d0_bg = (const float*)d_in[10];
  const float* d0_wc = (const float*)d_in[11];
  const float* d0_bc = (const float*)d_in[12];
  const float* d1_wg = (const float*)d_in[13];
  const float* d1_bg = (const float*)d_in[14];
  const float* d1_wc = (const float*)d_in[15];
  const float* d1_bc = (const float*)d_in[16];
  const float* fw    = (const float*)d_in[17];
  const float* fb    = (const float*)d_in[18];
  float* out = (float*)d_out;

  // workspace layout (floats)
  float* ws = (float*)d_ws;
  float* y1g = ws;                               // 64*100*64*128 = 52,428,800
  float* h0f = y1g + (size_t)B_ * T_ * 64 * F_;  // 64*32*128     =    262,144
  float* wp = h0f + (size_t)B_ * 32 * F_;
  float* wT_e0g = wp; wp += 33 * 3 * 64;
  float* wT_e0c = wp; wp += 33 * 3 * 32;
  float* wT_e1g = wp; wp += 96 * 3 * 128;
  float* wT_e1c = wp; wp += 96 * 3 * 64;
  float* wT_d0g = wp; wp += 128 * 3 * 128;
  float* wT_d0c = wp; wp += 128 * 3 * 64;
  float* wT_d1g = wp; wp += 96 * 3 * 64;
  float* wT_d1c = wp; wp += 96 * 3 * 32;

  auto rp = [&](const float* src, float* dst, int CO, int CI) {
    const int n = CO * CI * 3;
    hipLaunchKernelGGL(repack_kernel, dim3((n + 255) / 256), dim3(256), 0, stream,
                       src, dst, CO, CI);
  };
  rp(e0_wg, wT_e0g, 64, 33);
  rp(e0_wc, wT_e0c, 32, 33);
  rp(e1_wg, wT_e1g, 128, 96);
  rp(e1_wc, wT_e1c, 64, 96);
  rp(d0_wg, wT_d0g, 128, 128);
  rp(d0_wc, wT_d0c, 64, 128);
  rp(d1_wg, wT_d1g, 64, 96);
  rp(d1_wc, wT_d1c, 32, 96);

  const int enc_lds = 225 * FP_ * 4;  // 117,000 B
  const int dec_lds = 288 * FP_ * 4;  // 149,760 B
  hipFuncSetAttribute((const void*)enc_kernel,
                      hipFuncAttributeMaxDynamicSharedMemorySize, enc_lds);
  hipFuncSetAttribute((const void*)dec_kernel,
                      hipFuncAttributeMaxDynamicSharedMemorySize, dec_lds);

  hipLaunchKernelGGL(enc_kernel, dim3(B_), dim3(512), enc_lds, stream,
                     x, wT_e0g, e0_bg, wT_e0c, e0_bc,
                     wT_e1g, e1_bg, wT_e1c, e1_bc, y1g, h0f);
  hipLaunchKernelGGL(dec_kernel, dim3(B_), dim3(512), dec_lds, stream,
                     y1g, h0f, wT_d0g, d0_bg, wT_d0c, d0_bc,
                     wT_d1g, d1_bg, wT_d1c, d1_bc, fw, fb, out);
}

// Round 2
// 22409.782 us; speedup vs baseline: 2.6272x; 2.6272x over previous
//
#include <hip/hip_runtime.h>
#include <cstdint>
#include <cstddef>

// ConvGRU autoencoder, fp32, round 2.
// Conv restructured: thread = (co-lane 0..31, f-group 0..31), 1024 threads/block.
// Weights repacked to [ci][co][k0,k1,k2,0] float4 quads -> per-lane coalesced
// 16B loads (lanes 0..31 = one 512B line; identical across waves -> L1 hits).
// Activations live in LDS (padded rows of FP_=132 floats, 16B-aligned rows);
// read as 2 broadcast ds_read_b128 per ci (conflict-free).

#define F_ 128
#define FP_ 132   // padded row stride (pad [0], data [1..128], zeros [129..131])
#define T_ 100
#define B_ 64

__device__ __forceinline__ float sigm(float x) { return 1.0f / (1.0f + expf(-x)); }

// 3-tap conv accumulate: NR input rows (LDS), CO output channels.
// acc: CP=CO/32 float4 accumulators (4 consecutive f's for CP strided co's).
// wq: float4 quad pointer already offset to (ci=0, co=colane); advances CO/ci.
template <int NR, int CO>
__device__ __forceinline__ void conv_tile(float4* __restrict__ acc,
                                          const float* __restrict__ rows,
                                          int fg4, const float4* __restrict__ wq) {
  constexpr int CP = CO / 32;
  const float* r = rows + fg4;
#pragma unroll 2
  for (int ci = 0; ci < NR; ++ci) {
    const float4 a0 = *(const float4*)(r);
    const float4 a1 = *(const float4*)(r + 4);
    const float v0 = a0.x, v1 = a0.y, v2 = a0.z, v3 = a0.w, v4 = a1.x, v5 = a1.y;
#pragma unroll
    for (int cp = 0; cp < CP; ++cp) {
      const float4 w = wq[cp * 32];
      acc[cp].x = fmaf(w.x, v0, fmaf(w.y, v1, fmaf(w.z, v2, acc[cp].x)));
      acc[cp].y = fmaf(w.x, v1, fmaf(w.y, v2, fmaf(w.z, v3, acc[cp].y)));
      acc[cp].z = fmaf(w.x, v2, fmaf(w.y, v3, fmaf(w.z, v4, acc[cp].z)));
      acc[cp].w = fmaf(w.x, v3, fmaf(w.y, v4, fmaf(w.z, v5, acc[cp].w)));
    }
    r += FP_;
    wq += CO;
  }
}

// One ConvGRU step. xin: CIN rows; h: H rows (updated in place); rh/ub scratch.
// 1024 threads: colane = tid&31, fg = tid>>5 (f-tile of 4).
template <int CIN, int H>
__device__ void gru_step(int tid, const float* __restrict__ xin,
                         float* __restrict__ h, float* __restrict__ rh,
                         float* __restrict__ ub,
                         const float* __restrict__ wgq, const float* __restrict__ bg,
                         const float* __restrict__ wcq, const float* __restrict__ bc) {
  const int colane = tid & 31;
  const int fg4 = (tid >> 5) << 2;
  const int pb = fg4 + 1;

  // ---- phase A: gates = conv([x;h], wg)+bg; r,u = sigmoid halves ----
  {
    constexpr int CO = 2 * H;
    constexpr int CP = CO / 32;
    float4 acc[CP];
#pragma unroll
    for (int cp = 0; cp < CP; ++cp) {
      const float b = bg[colane + 32 * cp];
      acc[cp] = make_float4(b, b, b, b);
    }
    conv_tile<CIN, CO>(acc, xin, fg4, (const float4*)wgq + colane);
    conv_tile<H, CO>(acc, h, fg4, (const float4*)wgq + (size_t)CIN * CO + colane);
#pragma unroll
    for (int cp = 0; cp < CP; ++cp) {
      const int co = colane + 32 * cp;
      const float a4[4] = {acc[cp].x, acc[cp].y, acc[cp].z, acc[cp].w};
      if (cp < CP / 2) {  // r half: co in [0,H)
#pragma unroll
        for (int j = 0; j < 4; ++j) {
          const int idx = co * FP_ + pb + j;
          rh[idx] = sigm(a4[j]) * h[idx];
        }
      } else {  // u half
#pragma unroll
        for (int j = 0; j < 4; ++j)
          ub[(co - H) * FP_ + pb + j] = sigm(a4[j]);
      }
    }
  }
  __syncthreads();

  // ---- phase B: c = tanh(conv([x; r*h], wc)+bc); h = (1-u)h + u c ----
  {
    constexpr int CP = H / 32;
    float4 acc[CP];
#pragma unroll
    for (int cp = 0; cp < CP; ++cp) {
      const float b = bc[colane + 32 * cp];
      acc[cp] = make_float4(b, b, b, b);
    }
    conv_tile<CIN, H>(acc, xin, fg4, (const float4*)wcq + colane);
    conv_tile<H, H>(acc, rh, fg4, (const float4*)wcq + (size_t)CIN * H + colane);
#pragma unroll
    for (int cp = 0; cp < CP; ++cp) {
      const int co = colane + 32 * cp;
      const float a4[4] = {acc[cp].x, acc[cp].y, acc[cp].z, acc[cp].w};
#pragma unroll
      for (int j = 0; j < 4; ++j) {
        const int idx = co * FP_ + pb + j;
        const float c = tanhf(a4[j]);
        const float uu = ub[idx];
        const float ho = h[idx];
        h[idx] = fmaf(uu, c - ho, ho);
      }
    }
  }
  __syncthreads();
}

// ---------------- encoder: e0 (1->32), e1 (32->64), emit y1 sequence ----------
__global__ __launch_bounds__(1024, 4) void enc_kernel(
    const float* __restrict__ x,
    const float* __restrict__ wgq0, const float* __restrict__ bg0,
    const float* __restrict__ wcq0, const float* __restrict__ bc0,
    const float* __restrict__ wgq1, const float* __restrict__ bg1,
    const float* __restrict__ wcq1, const float* __restrict__ bc1,
    float* __restrict__ y1g, float* __restrict__ h0f) {
  extern __shared__ float smem[];
  float* xbuf = smem;            // 1 row
  float* h0 = xbuf + FP_;        // 32 rows
  float* h1 = h0 + 32 * FP_;     // 64 rows
  float* rh = h1 + 64 * FP_;     // 64 rows
  float* ub = rh + 64 * FP_;     // 64 rows -> total 225 rows
  const int tid = threadIdx.x;
  const int b = blockIdx.x;

  for (int i = tid; i < 225 * FP_; i += 1024) smem[i] = 0.0f;
  __syncthreads();

  for (int t = 0; t < T_; ++t) {
    if (tid < F_) xbuf[1 + tid] = x[((size_t)b * T_ + t) * F_ + tid];
    __syncthreads();
    gru_step<1, 32>(tid, xbuf, h0, rh, ub, wgq0, bg0, wcq0, bc0);
    gru_step<32, 64>(tid, h0, h1, rh, ub, wgq1, bg1, wcq1, bc1);
    float* dst = y1g + ((size_t)b * T_ + t) * 64 * F_;
    for (int i = tid; i < 64 * F_; i += 1024)
      dst[i] = h1[(i >> 7) * FP_ + 1 + (i & (F_ - 1))];
  }
  __syncthreads();
  for (int i = tid; i < 32 * F_; i += 1024)
    h0f[(size_t)b * 32 * F_ + i] = h0[(i >> 7) * FP_ + 1 + (i & (F_ - 1))];
}

// --------- decoder: d0 (64->64), d1 (64->32), fused 1x1 conv to output --------
__global__ __launch_bounds__(1024, 4) void dec_kernel(
    const float* __restrict__ y1g, const float* __restrict__ h0f,
    const float* __restrict__ wgq0, const float* __restrict__ bg0,
    const float* __restrict__ wcq0, const float* __restrict__ bc0,
    const float* __restrict__ wgq1, const float* __restrict__ bg1,
    const float* __restrict__ wcq1, const float* __restrict__ bc1,
    const float* __restrict__ fw, const float* __restrict__ fb,
    float* __restrict__ out) {
  extern __shared__ float smem[];
  float* y1t = smem;             // 64 rows
  float* hd0 = y1t + 64 * FP_;   // 64 rows
  float* hd1 = hd0 + 64 * FP_;   // 32 rows
  float* rh = hd1 + 32 * FP_;    // 64 rows
  float* ub = rh + 64 * FP_;     // 64 rows -> total 288 rows
  const int tid = threadIdx.x;
  const int b = blockIdx.x;

  for (int i = tid; i < 288 * FP_; i += 1024) smem[i] = 0.0f;
  __syncthreads();

  {  // init: hd0 = h1_final = y1[t=99]; hd1 = h0_final
    const float* s1 = y1g + ((size_t)b * T_ + (T_ - 1)) * 64 * F_;
    for (int i = tid; i < 64 * F_; i += 1024)
      hd0[(i >> 7) * FP_ + 1 + (i & (F_ - 1))] = s1[i];
    const float* s2 = h0f + (size_t)b * 32 * F_;
    for (int i = tid; i < 32 * F_; i += 1024)
      hd1[(i >> 7) * FP_ + 1 + (i & (F_ - 1))] = s2[i];
  }
  __syncthreads();

  for (int t = 0; t < T_; ++t) {
    const float* src = y1g + ((size_t)b * T_ + t) * 64 * F_;
    for (int i = tid; i < 64 * F_; i += 1024)
      y1t[(i >> 7) * FP_ + 1 + (i & (F_ - 1))] = src[i];
    __syncthreads();
    gru_step<64, 64>(tid, y1t, hd0, rh, ub, wgq0, bg0, wcq0, bc0);
    gru_step<64, 32>(tid, hd0, hd1, rh, ub, wgq1, bg1, wcq1, bc1);
    if (tid < F_) {  // final 1x1 conv over 32 channels
      float a = fb[0];
#pragma unroll
      for (int c = 0; c < 32; ++c) a = fmaf(fw[c], hd1[c * FP_ + 1 + tid], a);
      out[((size_t)b * T_ + t) * F_ + tid] = a;
    }
  }
}

// Repack (CO,CI,3,3) -> float4 quads [ci][co][k0,k1,k2,0], kw==1 column only.
__global__ void repack_quad(const float* __restrict__ src, float* __restrict__ dst,
                            int CO, int CI) {
  const int n = CI * CO;
  for (int i = blockIdx.x * blockDim.x + threadIdx.x; i < n;
       i += gridDim.x * blockDim.x) {
    const int ci = i / CO;
    const int co = i - ci * CO;
    const float* s = src + (size_t)(co * CI + ci) * 9 + 1;
    float4 q;
    q.x = s[0]; q.y = s[3]; q.z = s[6]; q.w = 0.0f;
    ((float4*)dst)[i] = q;
  }
}

extern "C" void kernel_launch(void* const* d_in, const int* in_sizes, int n_in,
                              void* d_out, int out_size, void* d_ws, size_t ws_size,
                              hipStream_t stream) {
  (void)in_sizes; (void)n_in; (void)out_size; (void)ws_size;
  const float* x     = (const float*)d_in[0];
  const float* e0_wg = (const float*)d_in[1];
  const float* e0_bg = (const float*)d_in[2];
  const float* e0_wc = (const float*)d_in[3];
  const float* e0_bc = (const float*)d_in[4];
  const float* e1_wg = (const float*)d_in[5];
  const float* e1_bg = (const float*)d_in[6];
  const float* e1_wc = (const float*)d_in[7];
  const float* e1_bc = (const float*)d_in[8];
  const float* d0_wg = (const float*)d_in[9];
  const float* d0_bg = (const float*)d_in[10];
  const float* d0_wc = (const float*)d_in[11];
  const float* d0_bc = (const float*)d_in[12];
  const float* d1_wg = (const float*)d_in[13];
  const float* d1_bg = (const float*)d_in[14];
  const float* d1_wc = (const float*)d_in[15];
  const float* d1_bc = (const float*)d_in[16];
  const float* fw    = (const float*)d_in[17];
  const float* fb    = (const float*)d_in[18];
  float* out = (float*)d_out;

  // workspace layout (floats)
  float* ws = (float*)d_ws;
  float* y1g = ws;                               // 64*100*64*128
  float* h0f = y1g + (size_t)B_ * T_ * 64 * F_;  // 64*32*128
  float* wp = h0f + (size_t)B_ * 32 * F_;
  float* wq_e0g = wp; wp += 33 * 64 * 4;
  float* wq_e0c = wp; wp += 33 * 32 * 4;
  float* wq_e1g = wp; wp += 96 * 128 * 4;
  float* wq_e1c = wp; wp += 96 * 64 * 4;
  float* wq_d0g = wp; wp += 128 * 128 * 4;
  float* wq_d0c = wp; wp += 128 * 64 * 4;
  float* wq_d1g = wp; wp += 96 * 64 * 4;
  float* wq_d1c = wp; wp += 96 * 32 * 4;

  auto rp = [&](const float* src, float* dst, int CO, int CI) {
    const int n = CI * CO;
    hipLaunchKernelGGL(repack_quad, dim3((n + 255) / 256), dim3(256), 0, stream,
                       src, dst, CO, CI);
  };
  rp(e0_wg, wq_e0g, 64, 33);
  rp(e0_wc, wq_e0c, 32, 33);
  rp(e1_wg, wq_e1g, 128, 96);
  rp(e1_wc, wq_e1c, 64, 96);
  rp(d0_wg, wq_d0g, 128, 128);
  rp(d0_wc, wq_d0c, 64, 128);
  rp(d1_wg, wq_d1g, 64, 96);
  rp(d1_wc, wq_d1c, 32, 96);

  const int enc_lds = 225 * FP_ * 4;  // 118,800 B
  const int dec_lds = 288 * FP_ * 4;  // 152,064 B
  hipFuncSetAttribute((const void*)enc_kernel,
                      hipFuncAttributeMaxDynamicSharedMemorySize, enc_lds);
  hipFuncSetAttribute((const void*)dec_kernel,
                      hipFuncAttributeMaxDynamicSharedMemorySize, dec_lds);

  hipLaunchKernelGGL(enc_kernel, dim3(B_), dim3(1024), enc_lds, stream,
                     x, wq_e0g, e0_bg, wq_e0c, e0_bc,
                     wq_e1g, e1_bg, wq_e1c, e1_bc, y1g, h0f);
  hipLaunchKernelGGL(dec_kernel, dim3(B_), dim3(1024), dec_lds, stream,
                     y1g, h0f, wq_d0g, d0_bg, wq_d0c, d0_bc,
                     wq_d1g, d1_bg, wq_d1c, d1_bc, fw, fb, out);
}

// Round 3
// 15250.772 us; speedup vs baseline: 3.8604x; 1.4694x over previous
//
#include <hip/hip_runtime.h>
#include <cstdint>
#include <cstddef>

// ConvGRU autoencoder, fp32, round 3.
// Re-tiled conv: each thread owns 1 output channel x FPT=CO/8 f-positions.
// Per ci, a thread loads ONE float4 weight quad (wave-unique 512B) and does
// 3*FPT FMAs -> FMA-issue-bound, not L1-bound. Activations in LDS rows of
// FP_=136 floats with data at cols [4..131] (halo cols 3 and 132 = 0) so all
// window reads AND all rh/ub/h float4 writes are 16B-aligned ds ops.

#define F_ 128
#define FP_ 136   // row stride: halo col3, data cols 4..131, halo col 132
#define T_ 100
#define B_ 64

__device__ __forceinline__ float sigm(float x) {
  return __builtin_amdgcn_rcpf(1.0f + __expf(-x));
}
__device__ __forceinline__ float tanh_fast(float x) {
  return fmaf(2.0f, __builtin_amdgcn_rcpf(1.0f + __expf(-2.0f * x)), -1.0f);
}

// 3-tap conv accumulate over NR input rows for one co, FPT f-positions.
// acc[FPT]; rows = LDS base of input rows; f0 = fg*FPT; wq = quad base + co.
// Window cols f0 .. f0+FPT+7 loaded as aligned float4; taps use w[o+3..o+5].
template <int NR, int CO>
__device__ __forceinline__ void conv_acc(float* __restrict__ acc,
                                         const float* __restrict__ rows,
                                         int f0, const float4* __restrict__ wq) {
  constexpr int FPT = CO / 8;
  constexpr int NQ = FPT / 4 + 2;
  const float* r = rows + f0;
#pragma unroll 2
  for (int ci = 0; ci < NR; ++ci) {
    const float4 k = wq[(size_t)ci * CO];
    float w[4 * NQ];
#pragma unroll
    for (int q = 0; q < NQ; ++q)
      *(float4*)(w + 4 * q) = *(const float4*)(r + 4 * q);
#pragma unroll
    for (int o = 0; o < FPT; ++o)
      acc[o] = fmaf(k.x, w[o + 3], fmaf(k.y, w[o + 4], fmaf(k.z, w[o + 5], acc[o])));
    r += FP_;
  }
}

// One ConvGRU step. 1024 threads. Thread mapping per phase (CO outputs):
// colane = tid&31 ; FG = 128/FPT f-groups ; fg = (tid>>5)%FG ; cg = (tid>>5)/FG
// co = colane + 32*cg ; f0 = fg*FPT.
template <int CIN, int H>
__device__ void gru_step(int tid, const float* __restrict__ xin,
                         float* __restrict__ h, float* __restrict__ rh,
                         float* __restrict__ ub,
                         const float4* __restrict__ wgq, const float* __restrict__ bg,
                         const float4* __restrict__ wcq, const float* __restrict__ bc) {
  const int colane = tid & 31;

  // ---- phase A: gates = conv([x;h], wg)+bg ; r-half -> rh = sig*h ; u -> ub
  {
    constexpr int CO = 2 * H;
    constexpr int FPT = CO / 8;
    constexpr int FG = 128 / FPT;
    const int fg = (tid >> 5) & (FG - 1);
    const int cg = (tid >> 5) / FG;
    const int co = colane + 32 * cg;
    const int f0 = fg * FPT;
    float acc[FPT];
    const float b = bg[co];
#pragma unroll
    for (int o = 0; o < FPT; ++o) acc[o] = b;
    conv_acc<CIN, CO>(acc, xin, f0, wgq + co);
    conv_acc<H, CO>(acc, h, f0, wgq + (size_t)CIN * CO + co);
    if (cg < CO / 64) {  // r half (co < H): rh = sigm * h
      const int base = co * FP_ + 4 + f0;
#pragma unroll
      for (int q = 0; q < FPT; q += 4) {
        const float4 h4 = *(const float4*)(h + base + q);
        float4 s;
        s.x = sigm(acc[q + 0]) * h4.x;
        s.y = sigm(acc[q + 1]) * h4.y;
        s.z = sigm(acc[q + 2]) * h4.z;
        s.w = sigm(acc[q + 3]) * h4.w;
        *(float4*)(rh + base + q) = s;
      }
    } else {  // u half
      const int base = (co - H) * FP_ + 4 + f0;
#pragma unroll
      for (int q = 0; q < FPT; q += 4) {
        float4 s;
        s.x = sigm(acc[q + 0]);
        s.y = sigm(acc[q + 1]);
        s.z = sigm(acc[q + 2]);
        s.w = sigm(acc[q + 3]);
        *(float4*)(ub + base + q) = s;
      }
    }
  }
  __syncthreads();

  // ---- phase B: c = tanh(conv([x; rh], wc)+bc) ; h = (1-u)h + u c
  {
    constexpr int CO = H;
    constexpr int FPT = CO / 8;
    constexpr int FG = 128 / FPT;
    const int fg = (tid >> 5) & (FG - 1);
    const int cg = (tid >> 5) / FG;
    const int co = colane + 32 * cg;
    const int f0 = fg * FPT;
    float acc[FPT];
    const float b = bc[co];
#pragma unroll
    for (int o = 0; o < FPT; ++o) acc[o] = b;
    conv_acc<CIN, CO>(acc, xin, f0, wcq + co);
    conv_acc<H, CO>(acc, rh, f0, wcq + (size_t)CIN * CO + co);
    const int base = co * FP_ + 4 + f0;
#pragma unroll
    for (int q = 0; q < FPT; q += 4) {
      const float4 h4 = *(const float4*)(h + base + q);
      const float4 u4 = *(const float4*)(ub + base + q);
      float4 o4;
      o4.x = fmaf(u4.x, tanh_fast(acc[q + 0]) - h4.x, h4.x);
      o4.y = fmaf(u4.y, tanh_fast(acc[q + 1]) - h4.y, h4.y);
      o4.z = fmaf(u4.z, tanh_fast(acc[q + 2]) - h4.z, h4.z);
      o4.w = fmaf(u4.w, tanh_fast(acc[q + 3]) - h4.w, h4.w);
      *(float4*)(h + base + q) = o4;
    }
  }
  __syncthreads();
}

// ---------------- encoder: e0 (1->32), e1 (32->64), emit y1 sequence ----------
__global__ __launch_bounds__(1024, 4) void enc_kernel(
    const float* __restrict__ x,
    const float4* __restrict__ wgq0, const float* __restrict__ bg0,
    const float4* __restrict__ wcq0, const float* __restrict__ bc0,
    const float4* __restrict__ wgq1, const float* __restrict__ bg1,
    const float4* __restrict__ wcq1, const float* __restrict__ bc1,
    float* __restrict__ y1g, float* __restrict__ h0f) {
  extern __shared__ float smem[];
  float* xbuf = smem;            // 1 row
  float* h0 = xbuf + FP_;        // 32 rows
  float* h1 = h0 + 32 * FP_;     // 64 rows
  float* rh = h1 + 64 * FP_;     // 64 rows
  float* ub = rh + 64 * FP_;     // 64 rows -> 225 rows total
  const int tid = threadIdx.x;
  const int b = blockIdx.x;

  for (int i = tid; i < 225 * (FP_ / 4); i += 1024)
    ((float4*)smem)[i] = make_float4(0.f, 0.f, 0.f, 0.f);
  __syncthreads();

  for (int t = 0; t < T_; ++t) {
    if (tid < F_) xbuf[4 + tid] = x[((size_t)b * T_ + t) * F_ + tid];
    __syncthreads();
    gru_step<1, 32>(tid, xbuf, h0, rh, ub, wgq0, bg0, wcq0, bc0);
    gru_step<32, 64>(tid, h0, h1, rh, ub, wgq1, bg1, wcq1, bc1);
    float4* dst = (float4*)(y1g + ((size_t)b * T_ + t) * 64 * F_);
    for (int i = tid; i < 64 * 32; i += 1024) {
      const int co = i >> 5, q = i & 31;
      dst[i] = *(const float4*)(h1 + co * FP_ + 4 + 4 * q);
    }
  }
  __syncthreads();
  float4* hdst = (float4*)(h0f + (size_t)b * 32 * F_);
  for (int i = tid; i < 32 * 32; i += 1024) {
    const int co = i >> 5, q = i & 31;
    hdst[i] = *(const float4*)(h0 + co * FP_ + 4 + 4 * q);
  }
}

// --------- decoder: d0 (64->64), d1 (64->32), fused 1x1 conv to output --------
__global__ __launch_bounds__(1024, 4) void dec_kernel(
    const float* __restrict__ y1g, const float* __restrict__ h0f,
    const float4* __restrict__ wgq0, const float* __restrict__ bg0,
    const float4* __restrict__ wcq0, const float* __restrict__ bc0,
    const float4* __restrict__ wgq1, const float* __restrict__ bg1,
    const float4* __restrict__ wcq1, const float* __restrict__ bc1,
    const float* __restrict__ fw, const float* __restrict__ fb,
    float* __restrict__ out) {
  extern __shared__ float smem[];
  float* y1t = smem;             // 64 rows
  float* hd0 = y1t + 64 * FP_;   // 64 rows
  float* hd1 = hd0 + 64 * FP_;   // 32 rows
  float* rh = hd1 + 32 * FP_;    // 64 rows
  float* ub = rh + 64 * FP_;     // 64 rows -> 288 rows total
  const int tid = threadIdx.x;
  const int b = blockIdx.x;

  for (int i = tid; i < 288 * (FP_ / 4); i += 1024)
    ((float4*)smem)[i] = make_float4(0.f, 0.f, 0.f, 0.f);
  __syncthreads();

  {  // init: hd0 = y1[t=T-1] (= h1 final); hd1 = h0 final
    const float4* s1 = (const float4*)(y1g + ((size_t)b * T_ + (T_ - 1)) * 64 * F_);
    for (int i = tid; i < 64 * 32; i += 1024) {
      const int co = i >> 5, q = i & 31;
      *(float4*)(hd0 + co * FP_ + 4 + 4 * q) = s1[i];
    }
    const float4* s2 = (const float4*)(h0f + (size_t)b * 32 * F_);
    for (int i = tid; i < 32 * 32; i += 1024) {
      const int co = i >> 5, q = i & 31;
      *(float4*)(hd1 + co * FP_ + 4 + 4 * q) = s2[i];
    }
  }
  __syncthreads();

  for (int t = 0; t < T_; ++t) {
    const float4* src = (const float4*)(y1g + ((size_t)b * T_ + t) * 64 * F_);
    for (int i = tid; i < 64 * 32; i += 1024) {
      const int co = i >> 5, q = i & 31;
      *(float4*)(y1t + co * FP_ + 4 + 4 * q) = src[i];
    }
    __syncthreads();
    gru_step<64, 64>(tid, y1t, hd0, rh, ub, wgq0, bg0, wcq0, bc0);
    gru_step<64, 32>(tid, hd0, hd1, rh, ub, wgq1, bg1, wcq1, bc1);
    if (tid < F_) {  // final 1x1 conv over 32 channels
      float a = fb[0];
#pragma unroll
      for (int c = 0; c < 32; ++c) a = fmaf(fw[c], hd1[c * FP_ + 4 + tid], a);
      out[((size_t)b * T_ + t) * F_ + tid] = a;
    }
  }
}

// Repack (CO,CI,3,3) -> float4 quads [ci][co] = (k0,k1,k2,0), kw==1 column only.
__global__ void repack_quad(const float* __restrict__ src, float* __restrict__ dst,
                            int CO, int CI) {
  const int n = CI * CO;
  for (int i = blockIdx.x * blockDim.x + threadIdx.x; i < n;
       i += gridDim.x * blockDim.x) {
    const int ci = i / CO;
    const int co = i - ci * CO;
    const float* s = src + (size_t)(co * CI + ci) * 9 + 1;
    float4 q;
    q.x = s[0]; q.y = s[3]; q.z = s[6]; q.w = 0.0f;
    ((float4*)dst)[i] = q;
  }
}

extern "C" void kernel_launch(void* const* d_in, const int* in_sizes, int n_in,
                              void* d_out, int out_size, void* d_ws, size_t ws_size,
                              hipStream_t stream) {
  (void)in_sizes; (void)n_in; (void)out_size; (void)ws_size;
  const float* x     = (const float*)d_in[0];
  const float* e0_wg = (const float*)d_in[1];
  const float* e0_bg = (const float*)d_in[2];
  const float* e0_wc = (const float*)d_in[3];
  const float* e0_bc = (const float*)d_in[4];
  const float* e1_wg = (const float*)d_in[5];
  const float* e1_bg = (const float*)d_in[6];
  const float* e1_wc = (const float*)d_in[7];
  const float* e1_bc = (const float*)d_in[8];
  const float* d0_wg = (const float*)d_in[9];
  const float* d0_bg = (const float*)d_in[10];
  const float* d0_wc = (const float*)d_in[11];
  const float* d0_bc = (const float*)d_in[12];
  const float* d1_wg = (const float*)d_in[13];
  const float* d1_bg = (const float*)d_in[14];
  const float* d1_wc = (const float*)d_in[15];
  const float* d1_bc = (const float*)d_in[16];
  const float* fw    = (const float*)d_in[17];
  const float* fb    = (const float*)d_in[18];
  float* out = (float*)d_out;

  // workspace layout (floats)
  float* ws = (float*)d_ws;
  float* y1g = ws;                               // 64*100*64*128
  float* h0f = y1g + (size_t)B_ * T_ * 64 * F_;  // 64*32*128
  float* wp = h0f + (size_t)B_ * 32 * F_;
  float* wq_e0g = wp; wp += 33 * 64 * 4;
  float* wq_e0c = wp; wp += 33 * 32 * 4;
  float* wq_e1g = wp; wp += 96 * 128 * 4;
  float* wq_e1c = wp; wp += 96 * 64 * 4;
  float* wq_d0g = wp; wp += 128 * 128 * 4;
  float* wq_d0c = wp; wp += 128 * 64 * 4;
  float* wq_d1g = wp; wp += 96 * 64 * 4;
  float* wq_d1c = wp; wp += 96 * 32 * 4;

  auto rp = [&](const float* src, float* dst, int CO, int CI) {
    const int n = CI * CO;
    hipLaunchKernelGGL(repack_quad, dim3((n + 255) / 256), dim3(256), 0, stream,
                       src, dst, CO, CI);
  };
  rp(e0_wg, wq_e0g, 64, 33);
  rp(e0_wc, wq_e0c, 32, 33);
  rp(e1_wg, wq_e1g, 128, 96);
  rp(e1_wc, wq_e1c, 64, 96);
  rp(d0_wg, wq_d0g, 128, 128);
  rp(d0_wc, wq_d0c, 64, 128);
  rp(d1_wg, wq_d1g, 64, 96);
  rp(d1_wc, wq_d1c, 32, 96);

  const int enc_lds = 225 * FP_ * 4;  // 122,400 B
  const int dec_lds = 288 * FP_ * 4;  // 156,672 B
  hipFuncSetAttribute((const void*)enc_kernel,
                      hipFuncAttributeMaxDynamicSharedMemorySize, enc_lds);
  hipFuncSetAttribute((const void*)dec_kernel,
                      hipFuncAttributeMaxDynamicSharedMemorySize, dec_lds);

  hipLaunchKernelGGL(enc_kernel, dim3(B_), dim3(1024), enc_lds, stream,
                     x, (const float4*)wq_e0g, e0_bg, (const float4*)wq_e0c, e0_bc,
                     (const float4*)wq_e1g, e1_bg, (const float4*)wq_e1c, e1_bc,
                     y1g, h0f);
  hipLaunchKernelGGL(dec_kernel, dim3(B_), dim3(1024), dec_lds, stream,
                     y1g, h0f,
                     (const float4*)wq_d0g, d0_bg, (const float4*)wq_d0c, d0_bc,
                     (const float4*)wq_d1g, d1_bg, (const float4*)wq_d1c, d1_bc,
                     fw, fb, out);
}

// Round 4
// 6688.267 us; speedup vs baseline: 8.8026x; 2.2802x over previous
//
#include <hip/hip_runtime.h>
#include <cstdint>
#include <cstddef>

// ConvGRU autoencoder, round 4: split-bf16 MFMA.
// Conv = GEMM D[co,f] = sum_{kk=(k,ci)} W[co][kk] * actT[kk][f+k-1] using
// mfma_f32_16x16x32_bf16. Values split as v = hi + lo (bf16 each); 3 MFMA
// terms (hi*hi + lo_w*hi + hi_w*lo) give ~2^-17 relative error. Recurrent h
// kept fp32 in LDS (transposed [f][co] for float4 access). Activations stored
// LDS-transposed bf16 in [cb][ROWS][8] subtiles -> B-fragment = 1 ds_read_b128.
// Weights pre-packed per MFMA fragment -> A-load = coalesced global b128.
// y1 (enc->dec stream) is plain bf16 (hi only).

#define F_ 128
#define T_ 100
#define B_ 64
#define ROWS_ 136  // rows 0..129 used (f=-1..128 halo), pad to 136 for banks

typedef __attribute__((ext_vector_type(4))) float f32x4;
typedef __attribute__((ext_vector_type(8))) short s16x8;

#define MFMA16(a, b, c) __builtin_amdgcn_mfma_f32_16x16x32_bf16(a, b, c, 0, 0, 0)

__device__ __forceinline__ ushort f2bf(float v) {
  unsigned u = __float_as_uint(v);
  unsigned r = (u + 0x7FFFu + ((u >> 16) & 1u)) >> 16;
  return (ushort)r;
}
__device__ __forceinline__ float bf2f(ushort b) {
  return __uint_as_float(((unsigned)b) << 16);
}
__device__ __forceinline__ float sigm(float x) {
  return __builtin_amdgcn_rcpf(1.0f + __expf(-x));
}
__device__ __forceinline__ float tanh_fast(float x) {
  return fmaf(2.0f, __builtin_amdgcn_rcpf(1.0f + __expf(-2.0f * x)), -1.0f);
}

// ---- MFMA conv: acc[COTW*FTW] over K = 3*CINH (kk = k*CINH + ci). ----
// actT layout: elem((col>>3)*ROWS_ + rf)*8 + (col&7); rf = f + 1 + (k-1).
// Lo-buffer only covers cols >= LOBASE. Packed W: [cot][ks][lane][8].
template <int CO, int CINH, int COLST, int FTW, int LOBASE>
__device__ __forceinline__ void conv_mfma(f32x4* __restrict__ acc,
                                          const ushort* __restrict__ aTh,
                                          const ushort* __restrict__ aTl,
                                          const ushort* __restrict__ Whi,
                                          const ushort* __restrict__ Wlo,
                                          int wv, int l) {
  constexpr int COTW = (CO / 16) / (2 * FTW);
  constexpr int NK = 3 * CINH / 32;
  const int ft0 = (wv % (8 / FTW)) * FTW;
  const int cot0 = (wv / (8 / FTW)) * COTW;
  const int m16 = l & 15, kb = l >> 4;
#pragma unroll
  for (int ks = 0; ks < NK; ++ks) {
    const int k = (ks * 32) / CINH;
    const int ci0 = (ks * 32) % CINH;
    const int colhi = COLST + ci0;
    s16x8 bhi[FTW];
#pragma unroll
    for (int j = 0; j < FTW; ++j) {
      const int rf = (ft0 + j) * 16 + m16 + k;
      bhi[j] = *(const s16x8*)&aTh[(((colhi >> 3) + kb) * ROWS_ + rf) * 8];
    }
    s16x8 ahi[COTW], alo[COTW];
#pragma unroll
    for (int i = 0; i < COTW; ++i) {
      const int off = (((cot0 + i) * NK + ks) * 64 + l) * 8;
      ahi[i] = *(const s16x8*)&Whi[off];
      alo[i] = *(const s16x8*)&Wlo[off];
    }
#pragma unroll
    for (int i = 0; i < COTW; ++i)
#pragma unroll
      for (int j = 0; j < FTW; ++j)
        acc[i * FTW + j] = MFMA16(ahi[i], bhi[j], acc[i * FTW + j]);
#pragma unroll
    for (int i = 0; i < COTW; ++i)
#pragma unroll
      for (int j = 0; j < FTW; ++j)
        acc[i * FTW + j] = MFMA16(alo[i], bhi[j], acc[i * FTW + j]);
    if (colhi >= LOBASE) {
      s16x8 blo[FTW];
#pragma unroll
      for (int j = 0; j < FTW; ++j) {
        const int rf = (ft0 + j) * 16 + m16 + k;
        blo[j] = *(const s16x8*)&aTl[((((colhi - LOBASE) >> 3) + kb) * ROWS_ + rf) * 8];
      }
#pragma unroll
      for (int i = 0; i < COTW; ++i)
#pragma unroll
        for (int j = 0; j < FTW; ++j)
          acc[i * FTW + j] = MFMA16(ahi[i], blo[j], acc[i * FTW + j]);
    }
  }
}

__device__ __forceinline__ void split_store4(const f32x4 v, ushort* __restrict__ aTh,
                                             ushort* __restrict__ aTl, int col, int rf,
                                             int lobase) {
  ushort4 hi, lo;
  hi.x = f2bf(v[0]); lo.x = f2bf(v[0] - bf2f(hi.x));
  hi.y = f2bf(v[1]); lo.y = f2bf(v[1] - bf2f(hi.y));
  hi.z = f2bf(v[2]); lo.z = f2bf(v[2] - bf2f(hi.z));
  hi.w = f2bf(v[3]); lo.w = f2bf(v[3] - bf2f(hi.w));
  *(ushort4*)&aTh[((col >> 3) * ROWS_ + rf) * 8 + (col & 7)] = hi;
  const int cl = col - lobase;
  *(ushort4*)&aTl[((cl >> 3) * ROWS_ + rf) * 8 + (col & 7)] = lo;
}

// D-fragment mapping (verified): f = ftile*16 + (l&15), co = cotile*16 + (l>>4)*4 + r.
template <int H, int HCOL, int FTW, int COTW, int HP, int LOBASE>
__device__ __forceinline__ void postA(const f32x4* __restrict__ acc,
                                      const float* __restrict__ bg,
                                      const float* __restrict__ hT,
                                      float* __restrict__ uT,
                                      ushort* __restrict__ aTh, ushort* __restrict__ aTl,
                                      int wv, int l) {
  const int ft0 = (wv % (8 / FTW)) * FTW;
  const int cot0 = (wv / (8 / FTW)) * COTW;
  const int m16 = l & 15, kb = l >> 4;
#pragma unroll
  for (int i = 0; i < COTW; ++i) {
    const int co0 = (cot0 + i) * 16 + kb * 4;
    const f32x4 b4 = *(const f32x4*)&bg[co0];
#pragma unroll
    for (int j = 0; j < FTW; ++j) {
      const int f = (ft0 + j) * 16 + m16;
      const f32x4 v = acc[i * FTW + j] + b4;
      f32x4 s;
      s[0] = sigm(v[0]); s[1] = sigm(v[1]); s[2] = sigm(v[2]); s[3] = sigm(v[3]);
      if (co0 < H) {  // r half: rh = sigm * h  -> into h's bf16 cols
        const f32x4 h4 = *(const f32x4*)&hT[f * HP + co0];
        split_store4(s * h4, aTh, aTl, HCOL + co0, f + 1, LOBASE);
      } else {  // u half -> fp32 scratch
        *(f32x4*)&uT[f * 68 + (co0 - H)] = s;
      }
    }
  }
}

template <int H, int HCOL, int FTW, int COTW, int HP, int LOBASE>
__device__ __forceinline__ void postB(const f32x4* __restrict__ acc,
                                      const float* __restrict__ bc,
                                      float* __restrict__ hT,
                                      const float* __restrict__ uT,
                                      ushort* __restrict__ aTh, ushort* __restrict__ aTl,
                                      int wv, int l) {
  const int ft0 = (wv % (8 / FTW)) * FTW;
  const int cot0 = (wv / (8 / FTW)) * COTW;
  const int m16 = l & 15, kb = l >> 4;
#pragma unroll
  for (int i = 0; i < COTW; ++i) {
    const int co0 = (cot0 + i) * 16 + kb * 4;
    const f32x4 b4 = *(const f32x4*)&bc[co0];
#pragma unroll
    for (int j = 0; j < FTW; ++j) {
      const int f = (ft0 + j) * 16 + m16;
      const f32x4 v = acc[i * FTW + j] + b4;
      f32x4 c4;
      c4[0] = tanh_fast(v[0]); c4[1] = tanh_fast(v[1]);
      c4[2] = tanh_fast(v[2]); c4[3] = tanh_fast(v[3]);
      const f32x4 u4 = *(const f32x4*)&uT[f * 68 + co0];
      f32x4 h4 = *(const f32x4*)&hT[f * HP + co0];
      h4 = h4 + u4 * (c4 - h4);
      *(f32x4*)&hT[f * HP + co0] = h4;
      split_store4(h4, aTh, aTl, HCOL + co0, f + 1, LOBASE);
    }
  }
}

// ---------------- encoder ----------------
// actT cols: 0=x, 1..7=pad0, 8..39=h0, 40..103=h1. 13 cb. LOBASE=0.
__global__ __launch_bounds__(1024, 1) void enc_kernel(
    const float* __restrict__ x,
    const ushort* wge0h, const ushort* wge0l, const float* bg0,
    const ushort* wce0h, const ushort* wce0l, const float* bc0,
    const ushort* wge1h, const ushort* wge1l, const float* bg1,
    const ushort* wce1h, const ushort* wce1l, const float* bc1,
    ushort* __restrict__ y1g, float* __restrict__ h0f, float* __restrict__ h1f) {
  extern __shared__ char smem[];
  ushort* aTh = (ushort*)smem;               // 13*136*8*2   = 28288 B
  ushort* aTl = (ushort*)(smem + 28288);     // 28288 B
  float* h0T = (float*)(smem + 56576);       // 128*36*4 = 18432 B
  float* h1T = (float*)(smem + 75008);       // 128*68*4 = 34816 B
  float* uT = (float*)(smem + 109824);       // 34816 B  -> total 144640
  const int tid = threadIdx.x, b = blockIdx.x;
  const int wv = tid >> 6, l = tid & 63;

  for (int i = tid; i < 144640 / 16; i += 1024)
    ((f32x4*)smem)[i] = (f32x4){0.f, 0.f, 0.f, 0.f};
  __syncthreads();

  for (int t = 0; t < T_; ++t) {
    if (tid < F_) {  // ingest x(t) -> col 0
      const float v = x[((size_t)b * T_ + t) * F_ + tid];
      const ushort h = f2bf(v);
      aTh[(tid + 1) * 8] = h;
      aTl[(tid + 1) * 8] = f2bf(v - bf2f(h));
    }
    __syncthreads();
    {  // e0 phase A (CO=64, CINH=64: cols 0..63, zero-w on 1..7 & 40..63)
      f32x4 acc[2] = {};
      conv_mfma<64, 64, 0, 2, 0>(acc, aTh, aTl, wge0h, wge0l, wv, l);
      __syncthreads();
      postA<32, 8, 2, 1, 36, 0>(acc, bg0, h0T, uT, aTh, aTl, wv, l);
    }
    __syncthreads();
    {  // e0 phase B
      f32x4 acc[1] = {};
      conv_mfma<32, 64, 0, 1, 0>(acc, aTh, aTl, wce0h, wce0l, wv, l);
      __syncthreads();
      postB<32, 8, 1, 1, 36, 0>(acc, bc0, h0T, uT, aTh, aTl, wv, l);
    }
    __syncthreads();
    {  // e1 phase A (CO=128, CINH=96: cols 8..103)
      f32x4 acc[4] = {};
      conv_mfma<128, 96, 8, 2, 0>(acc, aTh, aTl, wge1h, wge1l, wv, l);
      __syncthreads();
      postA<64, 40, 2, 2, 68, 0>(acc, bg1, h1T, uT, aTh, aTl, wv, l);
    }
    __syncthreads();
    {  // e1 phase B
      f32x4 acc[2] = {};
      conv_mfma<64, 96, 8, 2, 0>(acc, aTh, aTl, wce1h, wce1l, wv, l);
      __syncthreads();
      postB<64, 40, 2, 1, 68, 0>(acc, bc1, h1T, uT, aTh, aTl, wv, l);
    }
    __syncthreads();
    {  // dump y1(t) = bf16(h1) from cols 40..103
      const int f = tid >> 3, c8 = tid & 7;
      const s16x8 v = *(const s16x8*)&aTh[((5 + c8) * ROWS_ + f + 1) * 8];
      *(s16x8*)&y1g[(((size_t)b * T_ + t) * F_ + f) * 64 + c8 * 8] = v;
    }
  }
  __syncthreads();
  for (int i = tid; i < 128 * 8; i += 1024) {
    const int f = i >> 3, cq = i & 7;
    *(f32x4*)&h0f[((size_t)b * F_ + f) * 32 + cq * 4] =
        *(const f32x4*)&h0T[f * 36 + cq * 4];
  }
  for (int i = tid; i < 128 * 16; i += 1024) {
    const int f = i >> 4, cq = i & 15;
    *(f32x4*)&h1f[((size_t)b * F_ + f) * 64 + cq * 4] =
        *(const f32x4*)&h1T[f * 68 + cq * 4];
  }
}

// ---------------- decoder ----------------
// actT cols: 0..63=y1 (hi only), 64..127=hd0, 128..159=hd1. 20 cb hi, 12 cb lo
// (lo covers cols 64..159, LOBASE=64).
__global__ __launch_bounds__(1024, 1) void dec_kernel(
    const ushort* __restrict__ y1g, const float* __restrict__ h0f,
    const float* __restrict__ h1f,
    const ushort* wgd0h, const ushort* wgd0l, const float* bg0,
    const ushort* wcd0h, const ushort* wcd0l, const float* bc0,
    const ushort* wgd1h, const ushort* wgd1l, const float* bg1,
    const ushort* wcd1h, const ushort* wcd1l, const float* bc1,
    const float* __restrict__ fw, const float* __restrict__ fb,
    float* __restrict__ out) {
  extern __shared__ char smem[];
  ushort* aTh = (ushort*)smem;                // 20*136*8*2 = 43520 B
  ushort* aTl = (ushort*)(smem + 43520);      // 12*136*8*2 = 26112 B
  float* hd0T = (float*)(smem + 69632);       // 128*68*4 = 34816
  float* hd1T = (float*)(smem + 104448);      // 128*36*4 = 18432
  float* uT = (float*)(smem + 122880);        // 34816 -> total 157696
  const int tid = threadIdx.x, b = blockIdx.x;
  const int wv = tid >> 6, l = tid & 63;

  for (int i = tid; i < 157696 / 16; i += 1024)
    ((f32x4*)smem)[i] = (f32x4){0.f, 0.f, 0.f, 0.f};
  __syncthreads();

  // init: hd0 = h1_final, hd1 = h0_final (fp32 + split-bf16 transposed)
  for (int i = tid; i < 128 * 16; i += 1024) {
    const int f = i >> 4, cq = i & 15;
    const f32x4 v = *(const f32x4*)&h1f[((size_t)b * F_ + f) * 64 + cq * 4];
    *(f32x4*)&hd0T[f * 68 + cq * 4] = v;
#pragma unroll
    for (int r = 0; r < 4; ++r) {
      const int col = 64 + cq * 4 + r;
      const ushort h = f2bf(v[r]);
      aTh[((col >> 3) * ROWS_ + f + 1) * 8 + (col & 7)] = h;
      aTl[(((col - 64) >> 3) * ROWS_ + f + 1) * 8 + (col & 7)] = f2bf(v[r] - bf2f(h));
    }
  }
  for (int i = tid; i < 128 * 8; i += 1024) {
    const int f = i >> 3, cq = i & 7;
    const f32x4 v = *(const f32x4*)&h0f[((size_t)b * F_ + f) * 32 + cq * 4];
    *(f32x4*)&hd1T[f * 36 + cq * 4] = v;
#pragma unroll
    for (int r = 0; r < 4; ++r) {
      const int col = 128 + cq * 4 + r;
      const ushort h = f2bf(v[r]);
      aTh[((col >> 3) * ROWS_ + f + 1) * 8 + (col & 7)] = h;
      aTl[(((col - 64) >> 3) * ROWS_ + f + 1) * 8 + (col & 7)] = f2bf(v[r] - bf2f(h));
    }
  }
  __syncthreads();

  for (int t = 0; t < T_; ++t) {
    {  // ingest y1(t) -> cols 0..63 (hi only)
      const int f = tid >> 3, c8 = tid & 7;
      const s16x8 v =
          *(const s16x8*)&y1g[(((size_t)b * T_ + t) * F_ + f) * 64 + c8 * 8];
      *(s16x8*)&aTh[(c8 * ROWS_ + f + 1) * 8] = v;
    }
    __syncthreads();
    {  // d0 phase A (CO=128, CINH=128)
      f32x4 acc[4] = {};
      conv_mfma<128, 128, 0, 2, 64>(acc, aTh, aTl, wgd0h, wgd0l, wv, l);
      __syncthreads();
      postA<64, 64, 2, 2, 68, 64>(acc, bg0, hd0T, uT, aTh, aTl, wv, l);
    }
    __syncthreads();
    {  // d0 phase B
      f32x4 acc[2] = {};
      conv_mfma<64, 128, 0, 2, 64>(acc, aTh, aTl, wcd0h, wcd0l, wv, l);
      __syncthreads();
      postB<64, 64, 2, 1, 68, 64>(acc, bc0, hd0T, uT, aTh, aTl, wv, l);
    }
    __syncthreads();
    {  // d1 phase A (CO=64, CINH=96: cols 64..159)
      f32x4 acc[2] = {};
      conv_mfma<64, 96, 64, 2, 64>(acc, aTh, aTl, wgd1h, wgd1l, wv, l);
      __syncthreads();
      postA<32, 128, 2, 1, 36, 64>(acc, bg1, hd1T, uT, aTh, aTl, wv, l);
    }
    __syncthreads();
    {  // d1 phase B
      f32x4 acc[1] = {};
      conv_mfma<32, 96, 64, 1, 64>(acc, aTh, aTl, wcd1h, wcd1l, wv, l);
      __syncthreads();
      postB<32, 128, 1, 1, 36, 64>(acc, bc1, hd1T, uT, aTh, aTl, wv, l);
    }
    __syncthreads();
    if (tid < F_) {  // final 1x1 conv
      float s = fb[0];
#pragma unroll
      for (int c = 0; c < 32; c += 4) {
        const f32x4 h4 = *(const f32x4*)&hd1T[tid * 36 + c];
        const f32x4 w4 = *(const f32x4*)&fw[c];
        s += h4[0] * w4[0] + h4[1] * w4[1] + h4[2] * w4[2] + h4[3] * w4[3];
      }
      out[((size_t)b * T_ + t) * F_ + tid] = s;
    }
  }
}

// ---- weight repack: (CO,CI,3,3) fp32 -> per-fragment split-bf16 ----
// dhi/dlo[((cot*NK + ks)*64 + lane)*8 + j] = W[cot*16 + (lane&15)]
//   [kk = ks*32 + (lane>>4)*8 + j], kk = k*CINH + c, col c -> ci (or zero).
__global__ void repack_mfma(const float* __restrict__ src, ushort* __restrict__ dhi,
                            ushort* __restrict__ dlo, int CO, int CI, int CINH,
                            int NK, int e0map) {
  const int n = (CO / 16) * NK * 64;
  for (int i = blockIdx.x * blockDim.x + threadIdx.x; i < n;
       i += gridDim.x * blockDim.x) {
    const int cot = i / (NK * 64);
    const int r = i - cot * NK * 64;
    const int ks = r >> 6, lph = r & 63;
    const int co = cot * 16 + (lph & 15);
    const int kb = lph >> 4;
#pragma unroll
    for (int j = 0; j < 8; ++j) {
      const int kk = ks * 32 + kb * 8 + j;
      const int k = kk / CINH, c = kk - k * CINH;
      int ci;
      if (e0map) ci = (c == 0) ? 0 : ((c >= 8 && c < 40) ? c - 7 : -1);
      else ci = (c < CI) ? c : -1;
      float w = 0.f;
      if (ci >= 0) w = src[((size_t)(co * CI + ci) * 3 + k) * 3 + 1];
      const ushort h = f2bf(w);
      dhi[(size_t)i * 8 + j] = h;
      dlo[(size_t)i * 8 + j] = f2bf(w - bf2f(h));
    }
  }
}

extern "C" void kernel_launch(void* const* d_in, const int* in_sizes, int n_in,
                              void* d_out, int out_size, void* d_ws, size_t ws_size,
                              hipStream_t stream) {
  (void)in_sizes; (void)n_in; (void)out_size; (void)ws_size;
  const float* x = (const float*)d_in[0];
  const float* e0_wg = (const float*)d_in[1];
  const float* e0_bg = (const float*)d_in[2];
  const float* e0_wc = (const float*)d_in[3];
  const float* e0_bc = (const float*)d_in[4];
  const float* e1_wg = (const float*)d_in[5];
  const float* e1_bg = (const float*)d_in[6];
  const float* e1_wc = (const float*)d_in[7];
  const float* e1_bc = (const float*)d_in[8];
  const float* d0_wg = (const float*)d_in[9];
  const float* d0_bg = (const float*)d_in[10];
  const float* d0_wc = (const float*)d_in[11];
  const float* d0_bc = (const float*)d_in[12];
  const float* d1_wg = (const float*)d_in[13];
  const float* d1_bg = (const float*)d_in[14];
  const float* d1_wc = (const float*)d_in[15];
  const float* d1_bc = (const float*)d_in[16];
  const float* fw = (const float*)d_in[17];
  const float* fb = (const float*)d_in[18];
  float* out = (float*)d_out;

  char* p = (char*)d_ws;
  ushort* y1g = (ushort*)p; p += (size_t)B_ * T_ * 128 * 64 * 2;   // 104.86 MB
  float* h0f = (float*)p;   p += (size_t)B_ * 128 * 32 * 4;
  float* h1f = (float*)p;   p += (size_t)B_ * 128 * 64 * 4;
  // packed weights: sizes = CO*3*CINH ushorts each (hi, lo)
  auto alloc_w = [&](int CO, int CINH) {
    ushort* q = (ushort*)p;
    p += (size_t)CO * 3 * CINH * 2;
    return q;
  };
  ushort* we0gh = alloc_w(64, 64);  ushort* we0gl = alloc_w(64, 64);
  ushort* we0ch = alloc_w(32, 64);  ushort* we0cl = alloc_w(32, 64);
  ushort* we1gh = alloc_w(128, 96); ushort* we1gl = alloc_w(128, 96);
  ushort* we1ch = alloc_w(64, 96);  ushort* we1cl = alloc_w(64, 96);
  ushort* wd0gh = alloc_w(128, 128); ushort* wd0gl = alloc_w(128, 128);
  ushort* wd0ch = alloc_w(64, 128);  ushort* wd0cl = alloc_w(64, 128);
  ushort* wd1gh = alloc_w(64, 96);  ushort* wd1gl = alloc_w(64, 96);
  ushort* wd1ch = alloc_w(32, 96);  ushort* wd1cl = alloc_w(32, 96);

  auto rp = [&](const float* src, ushort* dhi, ushort* dlo, int CO, int CI,
                int CINH, int e0map) {
    const int NK = 3 * CINH / 32;
    const int n = (CO / 16) * NK * 64;
    hipLaunchKernelGGL(repack_mfma, dim3((n + 255) / 256), dim3(256), 0, stream,
                       src, dhi, dlo, CO, CI, CINH, NK, e0map);
  };
  rp(e0_wg, we0gh, we0gl, 64, 33, 64, 1);
  rp(e0_wc, we0ch, we0cl, 32, 33, 64, 1);
  rp(e1_wg, we1gh, we1gl, 128, 96, 96, 0);
  rp(e1_wc, we1ch, we1cl, 64, 96, 96, 0);
  rp(d0_wg, wd0gh, wd0gl, 128, 128, 128, 0);
  rp(d0_wc, wd0ch, wd0cl, 64, 128, 128, 0);
  rp(d1_wg, wd1gh, wd1gl, 64, 96, 96, 0);
  rp(d1_wc, wd1ch, wd1cl, 32, 96, 96, 0);

  const int enc_lds = 144640;
  const int dec_lds = 157696;
  hipFuncSetAttribute((const void*)enc_kernel,
                      hipFuncAttributeMaxDynamicSharedMemorySize, enc_lds);
  hipFuncSetAttribute((const void*)dec_kernel,
                      hipFuncAttributeMaxDynamicSharedMemorySize, dec_lds);

  hipLaunchKernelGGL(enc_kernel, dim3(B_), dim3(1024), enc_lds, stream, x,
                     we0gh, we0gl, e0_bg, we0ch, we0cl, e0_bc,
                     we1gh, we1gl, e1_bg, we1ch, we1cl, e1_bc, y1g, h0f, h1f);
  hipLaunchKernelGGL(dec_kernel, dim3(B_), dim3(1024), dec_lds, stream, y1g,
                     h0f, h1f,
                     wd0gh, wd0gl, d0_bg, wd0ch, wd0cl, d0_bc,
                     wd1gh, wd1gl, d1_bg, wd1ch, wd1cl, d1_bc, fw, fb, out);
}

// Round 5
// 2143.312 us; speedup vs baseline: 27.4687x; 3.1205x over previous
//
#include <hip/hip_runtime.h>
#include <cstdint>
#include <cstddef>

// ConvGRU autoencoder, round 5: layer-pipelined persistent kernel, f16 MFMA.
// 256 blocks = 4 stages (e0,e1,d0,d1) x 64 batch. Each block runs one layer's
// full T=100 recurrence: gate weights persistent in VGPRs, candidate weights
// persistent in LDS -> weights fetched ONCE (was 1.7GB/dispatch refetch).
// Per-t activations handed off via ring buffers + device-scope flags;
// e0||e1 and d0||d1 overlap (decoder starts after encoder: h-init dependency).
// h master state fp32 in LDS; u-gate kept in registers (phase A/B tiles match).

#define F_ 128
#define T_ 100
#define B_ 64
#define ROWSP 138  // aT row pitch: cb stride 2208B = +8 banks -> no cb aliasing
#define RING 8

typedef _Float16 f16;
typedef __attribute__((ext_vector_type(4))) float f32x4;
typedef __attribute__((ext_vector_type(8))) _Float16 f16x8;
typedef __attribute__((ext_vector_type(4))) _Float16 f16x4;

#define MFMA(a, b, c) __builtin_amdgcn_mfma_f32_16x16x32_f16(a, b, c, 0, 0, 0)

__device__ __forceinline__ float sigm(float x) {
  return __builtin_amdgcn_rcpf(1.0f + __expf(-x));
}
__device__ __forceinline__ float tanh_fast(float x) {
  return fmaf(2.0f, __builtin_amdgcn_rcpf(1.0f + __expf(-2.0f * x)), -1.0f);
}

__device__ __forceinline__ void spin_ge(const int* p, int v) {
  while (__hip_atomic_load(p, __ATOMIC_RELAXED, __HIP_MEMORY_SCOPE_AGENT) < v)
    __builtin_amdgcn_s_sleep(4);
  (void)__hip_atomic_load(p, __ATOMIC_ACQUIRE, __HIP_MEMORY_SCOPE_AGENT);
  __threadfence();
}
__device__ __forceinline__ void publish(int* p, int v) {
  __threadfence();
  __hip_atomic_store(p, v, __ATOMIC_RELEASE, __HIP_MEMORY_SCOPE_AGENT);
}

// One GRU layer, full recurrence. aT: f16 activations [cb][row(138)][8] with
// halo rows 0 and 129 zero; cols [0,HCOL) = input x, [HCOL,HCOL+H) = h / r*h.
// hT: fp32 h [f][HP]. Gate weights aR/aU in regs; cand weights in LDS.
// Wave tiling: cot_r = w&(NCR-1), ft0 = (w/NCR)*FTW, FTW = NCR = H/16; phase A
// computes (cot_r, cot_r+NCR) x FTW tiles, phase B (cot_r) x FTW -> u in regs.
template <int STAGE, int CINH, int H, int NK, int HCOL>
__device__ void run_stage(const int b, const int tid,
                          const f16* __restrict__ gW, const f16* __restrict__ cW,
                          const float* __restrict__ bg, const float* __restrict__ bc,
                          const float* __restrict__ x,
                          const f16* __restrict__ inBuf, f16* __restrict__ outBuf,
                          const f16* __restrict__ initHsrc, f16* __restrict__ h0fDst,
                          float* __restrict__ out, const float* __restrict__ fw,
                          const float* __restrict__ fb, int* __restrict__ flags) {
  constexpr int NCR = H / 16;
  constexpr int FTW = NCR;
  constexpr int CB = CINH / 8;
  constexpr int HP = H + 4;
  int* fP0 = flags;         // e0 -> e1 per-t
  int* fC1 = flags + 1024;  // e1 consumed (backpressure on e0)
  int* fP1 = flags + 2048;  // e1 per-t (d0 waits for == T)
  int* fP2 = flags + 3072;  // d0 -> d1 per-t
  int* fC3 = flags + 4096;  // d1 consumed (backpressure on d0)
  int* fD0 = flags + 5120;  // e0 fully done (h0 final ready)

  extern __shared__ char smem[];
  f16* aT = (f16*)smem;                                      // CB*138*8 f16
  float* hT = (float*)(smem + CB * ROWSP * 16);              // 128*HP f32
  f16* wcs = (f16*)(smem + CB * ROWSP * 16 + 128 * HP * 4);  // NCR*NK*512 f16

  for (int i = tid; i < (CB * ROWSP * 16 + 128 * HP * 4) / 16; i += 512)
    ((f32x4*)smem)[i] = (f32x4){0.f, 0.f, 0.f, 0.f};
  constexpr int CWN = NCR * NK * 512;
  for (int i = tid; i < CWN / 8; i += 512)
    *(f16x8*)&wcs[i * 8] = *(const f16x8*)&cW[i * 8];

  const int w = tid >> 6, l = tid & 63;
  const int m16 = l & 15, kb = l >> 4, kb4 = (l >> 4) * 4;
  const int cot_r = w & (NCR - 1);
  const int ft0 = (w / NCR) * FTW;
  const int co0 = cot_r * 16 + kb4;

  f16x8 aR[NK], aU[NK];  // persistent gate weights
#pragma unroll
  for (int ks = 0; ks < NK; ++ks) {
    aR[ks] = *(const f16x8*)&gW[((cot_r * NK + ks) * 64 + l) * 8];
    aU[ks] = *(const f16x8*)&gW[(((cot_r + NCR) * NK + ks) * 64 + l) * 8];
  }
  __syncthreads();

  if constexpr (STAGE == 2 || STAGE == 3) {  // decoder h-init from encoder finals
    if (tid == 0) {
      if constexpr (STAGE == 2) spin_ge(fP1 + b * 16, T_);
      else spin_ge(fD0 + b * 16, 1);
    }
    __syncthreads();
    for (int i = tid; i < (H / 8) * 128; i += 512) {
      const int cb = i >> 7, f = i & 127;
      const f16x8 v = *(const f16x8*)&initHsrc[i * 8];
      *(f16x8*)&aT[(((HCOL >> 3) + cb) * ROWSP + f + 1) * 8] = v;
#pragma unroll
      for (int r = 0; r < 8; ++r) hT[f * HP + cb * 8 + r] = (float)v[r];
    }
    __syncthreads();
  }

  for (int t = 0; t < T_; ++t) {
    if (tid == 0) {
      if constexpr (STAGE == 1) spin_ge(fP0 + b * 16, t + 1);
      if constexpr (STAGE == 3) spin_ge(fP2 + b * 16, t + 1);
      if constexpr (STAGE == 0) { if (t >= RING) spin_ge(fC1 + b * 16, t - RING + 1); }
      if constexpr (STAGE == 2) { if (t >= RING) spin_ge(fC3 + b * 16, t - RING + 1); }
    }
    __syncthreads();  // B1: flags satisfied
    // ---- ingest input x(t) into aT cols [0, HCOL_x) ----
    if constexpr (STAGE == 0) {
      if (tid < F_) aT[(tid + 1) * 8] = (f16)x[((size_t)b * T_ + t) * F_ + tid];
    } else {
      const f16* src;
      if constexpr (STAGE == 1)
        src = inBuf + ((size_t)b * RING + (t & (RING - 1))) * (32 * 128);
      else if constexpr (STAGE == 2)
        src = inBuf + ((size_t)b * T_ + t) * (64 * 128);
      else
        src = inBuf + ((size_t)b * RING + (t & (RING - 1))) * (64 * 128);
      constexpr int XC = (STAGE == 1) ? 32 : 64;
#pragma unroll
      for (int i0 = 0; i0 < XC * 16; i0 += 512) {
        const int i = i0 + tid;
        const int cb = i >> 7, f = i & 127;
        *(f16x8*)&aT[(cb * ROWSP + f + 1) * 8] = *(const f16x8*)&src[i * 8];
      }
    }
    __syncthreads();  // B2: aT ready; slot consumed
    if (tid == 0) {
      if constexpr (STAGE == 1) publish(fC1 + b * 16, t + 1);
      if constexpr (STAGE == 3) publish(fC3 + b * 16, t + 1);
    }
    // ---- conv A: gates over [x; h] ----
    f32x4 accR[FTW], accU[FTW];
#pragma unroll
    for (int j = 0; j < FTW; ++j) {
      accR[j] = (f32x4){0.f, 0.f, 0.f, 0.f};
      accU[j] = (f32x4){0.f, 0.f, 0.f, 0.f};
    }
#pragma unroll
    for (int ks = 0; ks < NK; ++ks) {
      const int k = ks / (CINH / 32);
      const int cb0 = (ks % (CINH / 32)) * 4;
      f16x8 bf[FTW];
#pragma unroll
      for (int j = 0; j < FTW; ++j)
        bf[j] = *(const f16x8*)&aT[((cb0 + kb) * ROWSP + (ft0 + j) * 16 + m16 + k) * 8];
#pragma unroll
      for (int j = 0; j < FTW; ++j) accR[j] = MFMA(aR[ks], bf[j], accR[j]);
#pragma unroll
      for (int j = 0; j < FTW; ++j) accU[j] = MFMA(aU[ks], bf[j], accU[j]);
    }
    __syncthreads();  // B3: all convA reads of h-cols done before rh overwrite
    // ---- post A: r-half -> rh (f16, overwrites h cols); u stays in regs ----
    f32x4 u[FTW];
    {
      const f32x4 bgR = *(const f32x4*)&bg[co0];
      const f32x4 bgU = *(const f32x4*)&bg[H + co0];
#pragma unroll
      for (int j = 0; j < FTW; ++j) {
        const int f = (ft0 + j) * 16 + m16;
        const f32x4 h4 = *(const f32x4*)&hT[f * HP + co0];
        f16x4 rh;
#pragma unroll
        for (int q = 0; q < 4; ++q) {
          u[j][q] = sigm(accU[j][q] + bgU[q]);
          rh[q] = (f16)(sigm(accR[j][q] + bgR[q]) * h4[q]);
        }
        *(f16x4*)&aT[(((HCOL + co0) >> 3) * ROWSP + f + 1) * 8 + (co0 & 7)] = rh;
      }
    }
    __syncthreads();  // B4: rh visible
    // ---- conv B: candidate over [x; r*h] ----
    f32x4 accB[FTW];
#pragma unroll
    for (int j = 0; j < FTW; ++j) accB[j] = (f32x4){0.f, 0.f, 0.f, 0.f};
#pragma unroll
    for (int ks = 0; ks < NK; ++ks) {
      const int k = ks / (CINH / 32);
      const int cb0 = (ks % (CINH / 32)) * 4;
      const f16x8 a = *(const f16x8*)&wcs[((cot_r * NK + ks) * 64 + l) * 8];
      f16x8 bf[FTW];
#pragma unroll
      for (int j = 0; j < FTW; ++j)
        bf[j] = *(const f16x8*)&aT[((cb0 + kb) * ROWSP + (ft0 + j) * 16 + m16 + k) * 8];
#pragma unroll
      for (int j = 0; j < FTW; ++j) accB[j] = MFMA(a, bf[j], accB[j]);
    }
    __syncthreads();  // B5: all convB reads done before h overwrite
    // ---- post B: h = (1-u)h + u*tanh(.) ; write hT, aT f16, output ----
    {
      const f32x4 bc4 = *(const f32x4*)&bc[co0];
      f16* dst = nullptr;
      if constexpr (STAGE == 0)
        dst = outBuf + ((size_t)b * RING + (t & (RING - 1))) * (32 * 128);
      else if constexpr (STAGE == 1)
        dst = outBuf + ((size_t)b * T_ + t) * (64 * 128);
      else if constexpr (STAGE == 2)
        dst = outBuf + ((size_t)b * RING + (t & (RING - 1))) * (64 * 128);
#pragma unroll
      for (int j = 0; j < FTW; ++j) {
        const int f = (ft0 + j) * 16 + m16;
        f32x4 h4 = *(const f32x4*)&hT[f * HP + co0];
#pragma unroll
        for (int q = 0; q < 4; ++q) {
          const float c = tanh_fast(accB[j][q] + bc4[q]);
          h4[q] = fmaf(u[j][q], c - h4[q], h4[q]);
        }
        *(f32x4*)&hT[f * HP + co0] = h4;
        f16x4 hh;
#pragma unroll
        for (int q = 0; q < 4; ++q) hh[q] = (f16)h4[q];
        *(f16x4*)&aT[(((HCOL + co0) >> 3) * ROWSP + f + 1) * 8 + (co0 & 7)] = hh;
        if constexpr (STAGE < 3)
          *(f16x4*)&dst[((co0 >> 3) * 128 + f) * 8 + (co0 & 7)] = hh;
      }
    }
    __syncthreads();  // B6: outputs + hT complete
    if (tid == 0) {
      if constexpr (STAGE == 0) publish(fP0 + b * 16, t + 1);
      if constexpr (STAGE == 1) publish(fP1 + b * 16, t + 1);
      if constexpr (STAGE == 2) publish(fP2 + b * 16, t + 1);
    }
    if constexpr (STAGE == 3) {  // final 1x1 conv (32 -> 1), fp32 out
      if (tid < F_) {
        float s = fb[0];
#pragma unroll
        for (int c = 0; c < 32; ++c) s = fmaf(fw[c], hT[tid * HP + c], s);
        out[((size_t)b * T_ + t) * F_ + tid] = s;
      }
    }
  }

  if constexpr (STAGE == 0) {  // publish final h0 for d1's init
    __syncthreads();
    if (tid < 512) {
      const int cb = tid >> 7, f = tid & 127;
      f16x8 v;
#pragma unroll
      for (int r = 0; r < 8; ++r) v[r] = (f16)hT[f * HP + cb * 8 + r];
      *(f16x8*)&h0fDst[tid * 8] = v;
    }
    __syncthreads();
    if (tid == 0) publish(fD0 + b * 16, 1);
  }
}

__global__ __launch_bounds__(512, 2) void pipe_kernel(
    const float* __restrict__ x, float* __restrict__ out,
    const f16* wgE0, const f16* wcE0, const float* bgE0, const float* bcE0,
    const f16* wgE1, const f16* wcE1, const float* bgE1, const float* bcE1,
    const f16* wgD0, const f16* wcD0, const float* bgD0, const float* bcD0,
    const f16* wgD1, const f16* wcD1, const float* bgD1, const float* bcD1,
    const float* fw, const float* fb,
    f16* Y0, f16* Y1, f16* Z0, f16* H0F, int* flags) {
  const int stage = blockIdx.x >> 6;
  const int b = blockIdx.x & 63;
  const int tid = threadIdx.x;
  if (stage == 0)
    run_stage<0, 64, 32, 6, 8>(b, tid, wgE0, wcE0, bgE0, bcE0, x, nullptr, Y0,
                               nullptr, H0F + (size_t)b * 4096, nullptr, nullptr,
                               nullptr, flags);
  else if (stage == 1)
    run_stage<1, 96, 64, 9, 32>(b, tid, wgE1, wcE1, bgE1, bcE1, nullptr, Y0, Y1,
                                nullptr, nullptr, nullptr, nullptr, nullptr, flags);
  else if (stage == 2)
    run_stage<2, 128, 64, 12, 64>(b, tid, wgD0, wcD0, bgD0, bcD0, nullptr, Y1, Z0,
                                  Y1 + ((size_t)b * T_ + T_ - 1) * 8192, nullptr,
                                  nullptr, nullptr, nullptr, flags);
  else
    run_stage<3, 96, 32, 9, 64>(b, tid, wgD1, wcD1, bgD1, bcD1, nullptr, Z0,
                                nullptr, H0F + (size_t)b * 4096, nullptr, out, fw,
                                fb, flags);
}

__global__ void zero_flags(int* f) {
  for (int i = threadIdx.x + blockIdx.x * blockDim.x; i < 6144;
       i += blockDim.x * gridDim.x)
    f[i] = 0;
}

// (CO,CI,3,3) fp32 -> f16 packed per MFMA A-fragment:
// dst[((cot*NK+ks)*64+lane)*8+j] = W[cot*16+(lane&15)][kk=ks*32+(lane>>4)*8+j],
// kk = k*CINH + c; c -> ci via identity (c<CI) or e0 map (x@0, h@8..39).
__global__ void repack_f16(const float* __restrict__ src, f16* __restrict__ dst,
                           int CO, int CI, int CINH, int NK, int e0map) {
  const int n = (CO / 16) * NK * 64;
  for (int i = blockIdx.x * blockDim.x + threadIdx.x; i < n;
       i += gridDim.x * blockDim.x) {
    const int cot = i / (NK * 64);
    const int r = i - cot * NK * 64;
    const int ks = r >> 6, lph = r & 63;
    const int co = cot * 16 + (lph & 15);
    const int kb = lph >> 4;
#pragma unroll
    for (int j = 0; j < 8; ++j) {
      const int kk = ks * 32 + kb * 8 + j;
      const int k = kk / CINH, c = kk - k * CINH;
      int ci;
      if (e0map) ci = (c == 0) ? 0 : ((c >= 8 && c < 40) ? c - 7 : -1);
      else ci = (c < CI) ? c : -1;
      float wv = 0.f;
      if (ci >= 0) wv = src[((size_t)(co * CI + ci) * 3 + k) * 3 + 1];
      dst[(size_t)i * 8 + j] = (f16)wv;
    }
  }
}

extern "C" void kernel_launch(void* const* d_in, const int* in_sizes, int n_in,
                              void* d_out, int out_size, void* d_ws, size_t ws_size,
                              hipStream_t stream) {
  (void)in_sizes; (void)n_in; (void)out_size; (void)ws_size;
  const float* x = (const float*)d_in[0];
  const float* e0_wg = (const float*)d_in[1];
  const float* e0_bg = (const float*)d_in[2];
  const float* e0_wc = (const float*)d_in[3];
  const float* e0_bc = (const float*)d_in[4];
  const float* e1_wg = (const float*)d_in[5];
  const float* e1_bg = (const float*)d_in[6];
  const float* e1_wc = (const float*)d_in[7];
  const float* e1_bc = (const float*)d_in[8];
  const float* d0_wg = (const float*)d_in[9];
  const float* d0_bg = (const float*)d_in[10];
  const float* d0_wc = (const float*)d_in[11];
  const float* d0_bc = (const float*)d_in[12];
  const float* d1_wg = (const float*)d_in[13];
  const float* d1_bg = (const float*)d_in[14];
  const float* d1_wc = (const float*)d_in[15];
  const float* d1_bc = (const float*)d_in[16];
  const float* fw = (const float*)d_in[17];
  const float* fb = (const float*)d_in[18];
  float* out = (float*)d_out;

  char* p = (char*)d_ws;
  int* flags = (int*)p;  p += 6144 * 4;                      // 24 KB, padded idx*16
  f16* Y0 = (f16*)p;     p += (size_t)B_ * RING * 32 * 128 * 2;   // 4.19 MB ring
  f16* Y1 = (f16*)p;     p += (size_t)B_ * T_ * 64 * 128 * 2;     // 104.9 MB full
  f16* Z0 = (f16*)p;     p += (size_t)B_ * RING * 64 * 128 * 2;   // 8.39 MB ring
  f16* H0F = (f16*)p;    p += (size_t)B_ * 32 * 128 * 2;          // 0.52 MB
  auto aw = [&](int n) { f16* q = (f16*)p; p += (size_t)n * 2; return q; };
  f16* wgE0 = aw(64 * 192);  f16* wcE0 = aw(32 * 192);
  f16* wgE1 = aw(128 * 288); f16* wcE1 = aw(64 * 288);
  f16* wgD0 = aw(128 * 384); f16* wcD0 = aw(64 * 384);
  f16* wgD1 = aw(64 * 288);  f16* wcD1 = aw(32 * 288);

  hipLaunchKernelGGL(zero_flags, dim3(6), dim3(1024), 0, stream, flags);
  auto rp = [&](const float* s, f16* d, int CO, int CI, int CINH, int e0m) {
    const int NK = 3 * CINH / 32;
    const int n = (CO / 16) * NK * 64;
    hipLaunchKernelGGL(repack_f16, dim3((n + 255) / 256), dim3(256), 0, stream,
                       s, d, CO, CI, CINH, NK, e0m);
  };
  rp(e0_wg, wgE0, 64, 33, 64, 1);
  rp(e0_wc, wcE0, 32, 33, 64, 1);
  rp(e1_wg, wgE1, 128, 96, 96, 0);
  rp(e1_wc, wcE1, 64, 96, 96, 0);
  rp(d0_wg, wgD0, 128, 128, 128, 0);
  rp(d0_wc, wcD0, 64, 128, 128, 0);
  rp(d1_wg, wgD1, 64, 96, 96, 0);
  rp(d1_wc, wcD1, 32, 96, 96, 0);

  const int lds = 119296;  // d0 stage max: aT 35328 + hT 34816 + wc 49152
  hipFuncSetAttribute((const void*)pipe_kernel,
                      hipFuncAttributeMaxDynamicSharedMemorySize, lds);
  hipLaunchKernelGGL(pipe_kernel, dim3(256), dim3(512), lds, stream,
                     x, out, wgE0, wcE0, e0_bg, e0_bc, wgE1, wcE1, e1_bg, e1_bc,
                     wgD0, wcD0, d0_bg, d0_bc, wgD1, wcD1, d1_bg, d1_bc,
                     fw, fb, Y0, Y1, Z0, H0F, flags);
}

// Round 6
// 1624.827 us; speedup vs baseline: 36.2341x; 1.3191x over previous
//
#include <hip/hip_runtime.h>
#include <cstdint>
#include <cstddef>

// ConvGRU autoencoder, round 6: single block per batch, all 4 layers in-block.
// No cross-block sync at all. h master state in REGISTERS (tiles identical
// across phase A, phase B, timesteps, and enc->dec init). e0->e1 and d0->d1
// hand off via LDS. Only y1 goes through global (bulk, phase-separated).
// Gate weights of big layers (e1,d0) persistent in VGPRs; e0/d1 gate +
// all candidate weights in LDS. r*h overwrites h cols (barrier-protected).
//
// LDS map (bytes):            enc phase              dec phase
//   [0,104448)   weights:     wgE0@0, wcE0@24576,    wcD0@0, wgD1@49152,
//                             wcE1@36864             wcD1@86016
//   [104448,146048) aT: f16 [cb][row 130][8], cols:
//       enc: x@0, h0@8-39 (->rh0->h0), h1@40-103 (->rh1->h1)
//       dec: y1@0-63, hd0@64-127 (->rh->h), hd1@128-159 (->rh->h)

#define F_ 128
#define T_ 100
#define B_ 64
#define ROWSP 130
#define AT_OFF 104448

typedef _Float16 f16;
typedef __attribute__((ext_vector_type(4))) float f32x4;
typedef __attribute__((ext_vector_type(8))) _Float16 f16x8;
typedef __attribute__((ext_vector_type(4))) _Float16 f16x4;

#define MFMA(a, b, c) __builtin_amdgcn_mfma_f32_16x16x32_f16(a, b, c, 0, 0, 0)

__device__ __forceinline__ float sigm(float x) {
  return __builtin_amdgcn_rcpf(1.0f + __expf(-x));
}
__device__ __forceinline__ float tanh_fast(float x) {
  return fmaf(2.0f, __builtin_amdgcn_rcpf(1.0f + __expf(-2.0f * x)), -1.0f);
}

// One GRU layer step. Wave tiling: FTW = NCR = H/16; cot_r = w&(NCR-1) is the
// output-channel tile (R half; U = cot_r+NCR), ft0 = (w/NCR)*FTW the f tiles.
// aT window cols [WINC*8, WINC*8 + NK*32/3); h cols at HC (overwritten by rh
// in postA, restored with new h in postB). hreg: thread's fp32 master h.
// Caller must __syncthreads() before the call (inputs ready) and after
// (h writes visible).
template <int NCR, int NK, int WINC, int HC, bool GREG, bool EMITY1>
__device__ __forceinline__ void gru_layer(
    f16* __restrict__ aT, const f16x8* __restrict__ aRreg,
    const f16x8* __restrict__ aUreg, const f16* __restrict__ gLds,
    const f16* __restrict__ cLds, const float* __restrict__ bg,
    const float* __restrict__ bc, f32x4* __restrict__ hreg,
    f16* __restrict__ y1dst, int w, int l) {
  constexpr int FTW = NCR;
  constexpr int NC3 = NK / 3;
  constexpr int H = 16 * NCR;
  const int m16 = l & 15, kb = l >> 4;
  const int cot_r = w & (NCR - 1);
  const int ft0 = (w / NCR) * FTW;
  const int co0 = cot_r * 16 + (kb << 2);

  // ---- conv A: gates over [x ; h] ----
  f32x4 accR[FTW], accU[FTW];
#pragma unroll
  for (int j = 0; j < FTW; ++j) {
    accR[j] = (f32x4){0.f, 0.f, 0.f, 0.f};
    accU[j] = (f32x4){0.f, 0.f, 0.f, 0.f};
  }
#pragma unroll
  for (int ks = 0; ks < NK; ++ks) {
    const int k = ks / NC3;
    const int cb = WINC + (ks % NC3) * 4 + kb;
    f16x8 bf[FTW];
#pragma unroll
    for (int j = 0; j < FTW; ++j)
      bf[j] = *(const f16x8*)&aT[(cb * ROWSP + (ft0 + j) * 16 + m16 + k) * 8];
    f16x8 wr, wu;
    if constexpr (GREG) {
      wr = aRreg[ks];
      wu = aUreg[ks];
    } else {
      wr = *(const f16x8*)&gLds[((cot_r * NK + ks) * 64 + l) * 8];
      wu = *(const f16x8*)&gLds[(((cot_r + NCR) * NK + ks) * 64 + l) * 8];
    }
#pragma unroll
    for (int j = 0; j < FTW; ++j) accR[j] = MFMA(wr, bf[j], accR[j]);
#pragma unroll
    for (int j = 0; j < FTW; ++j) accU[j] = MFMA(wu, bf[j], accU[j]);
  }
  __syncthreads();  // conv A reads done -> rh may overwrite h cols

  // ---- post A: rh = sigm(R)*h into h cols; u kept in regs ----
  f32x4 u[FTW];
  {
    const f32x4 bR = *(const f32x4*)&bg[co0];
    const f32x4 bU = *(const f32x4*)&bg[H + co0];
    const int col = HC + co0;
#pragma unroll
    for (int j = 0; j < FTW; ++j) {
      const int row = (ft0 + j) * 16 + m16 + 1;
      f16x4 rh;
#pragma unroll
      for (int q = 0; q < 4; ++q) {
        u[j][q] = sigm(accU[j][q] + bU[q]);
        rh[q] = (f16)(sigm(accR[j][q] + bR[q]) * hreg[j][q]);
      }
      *(f16x4*)&aT[((col >> 3) * ROWSP + row) * 8 + (col & 7)] = rh;
    }
  }
  __syncthreads();  // rh visible

  // ---- conv B: candidate over [x ; r*h] ----
  f32x4 accC[FTW];
#pragma unroll
  for (int j = 0; j < FTW; ++j) accC[j] = (f32x4){0.f, 0.f, 0.f, 0.f};
#pragma unroll
  for (int ks = 0; ks < NK; ++ks) {
    const int k = ks / NC3;
    const int cb = WINC + (ks % NC3) * 4 + kb;
    f16x8 bf[FTW];
#pragma unroll
    for (int j = 0; j < FTW; ++j)
      bf[j] = *(const f16x8*)&aT[(cb * ROWSP + (ft0 + j) * 16 + m16 + k) * 8];
    const f16x8 wc = *(const f16x8*)&cLds[((cot_r * NK + ks) * 64 + l) * 8];
#pragma unroll
    for (int j = 0; j < FTW; ++j) accC[j] = MFMA(wc, bf[j], accC[j]);
  }
  __syncthreads();  // conv B reads done -> h may overwrite rh cols

  // ---- post B: h = (1-u)h + u*tanh(C); restore h cols; optional y1 emit ----
  {
    const f32x4 b4 = *(const f32x4*)&bc[co0];
    const int col = HC + co0;
#pragma unroll
    for (int j = 0; j < FTW; ++j) {
      const int row = (ft0 + j) * 16 + m16 + 1;
      f16x4 hh;
#pragma unroll
      for (int q = 0; q < 4; ++q) {
        const float c = tanh_fast(accC[j][q] + b4[q]);
        hreg[j][q] = fmaf(u[j][q], c - hreg[j][q], hreg[j][q]);
        hh[q] = (f16)hreg[j][q];
      }
      *(f16x4*)&aT[((col >> 3) * ROWSP + row) * 8 + (col & 7)] = hh;
      if constexpr (EMITY1) {
        const int f = (ft0 + j) * 16 + m16;
        *(f16x4*)&y1dst[((co0 >> 3) * 128 + f) * 8 + (co0 & 7)] = hh;
      }
    }
  }
}

__global__ __launch_bounds__(512, 1) void ae_kernel(
    const float* __restrict__ x, float* __restrict__ out,
    const f16* __restrict__ wgE0, const f16* __restrict__ wcE0,
    const float* __restrict__ bgE0, const float* __restrict__ bcE0,
    const f16* __restrict__ wgE1, const f16* __restrict__ wcE1,
    const float* __restrict__ bgE1, const float* __restrict__ bcE1,
    const f16* __restrict__ wgD0, const f16* __restrict__ wcD0,
    const float* __restrict__ bgD0, const float* __restrict__ bcD0,
    const f16* __restrict__ wgD1, const f16* __restrict__ wcD1,
    const float* __restrict__ bgD1, const float* __restrict__ bcD1,
    const float* __restrict__ fw, const float* __restrict__ fb,
    f16* __restrict__ y1g) {
  extern __shared__ char smem[];
  f16* aT = (f16*)(smem + AT_OFF);
  const int tid = threadIdx.x, b = blockIdx.x;
  const int w = tid >> 6, l = tid & 63;

  // zero aT (20 cb x 130 rows x 16B = 41600 B)
  for (int i = tid; i < 41600 / 16; i += 512)
    ((f32x4*)(smem + AT_OFF))[i] = (f32x4){0.f, 0.f, 0.f, 0.f};
  // load encoder LDS weights
  for (int i = tid; i < 1536; i += 512)
    ((f16x8*)(smem + 0))[i] = ((const f16x8*)wgE0)[i];
  for (int i = tid; i < 768; i += 512)
    ((f16x8*)(smem + 24576))[i] = ((const f16x8*)wcE0)[i];
  for (int i = tid; i < 2304; i += 512)
    ((f16x8*)(smem + 36864))[i] = ((const f16x8*)wcE1)[i];

  // e1 gate weights -> VGPRs
  f16x8 aR1[9], aU1[9];
  {
    const int cr = w & 3;
#pragma unroll
    for (int ks = 0; ks < 9; ++ks) {
      aR1[ks] = *(const f16x8*)&wgE1[((cr * 9 + ks) * 64 + l) * 8];
      aU1[ks] = *(const f16x8*)&wgE1[(((cr + 4) * 9 + ks) * 64 + l) * 8];
    }
  }
  f32x4 h0r[2], h1r[4];
#pragma unroll
  for (int j = 0; j < 2; ++j) h0r[j] = (f32x4){0.f, 0.f, 0.f, 0.f};
#pragma unroll
  for (int j = 0; j < 4; ++j) h1r[j] = (f32x4){0.f, 0.f, 0.f, 0.f};
  __syncthreads();

  // ================= encoder =================
  for (int t = 0; t < T_; ++t) {
    if (tid < F_) aT[(tid + 1) * 8] = (f16)x[((size_t)b * T_ + t) * F_ + tid];
    __syncthreads();
    gru_layer<2, 6, 0, 8, false, false>(aT, nullptr, nullptr, (const f16*)smem,
                                        (const f16*)(smem + 24576), bgE0, bcE0,
                                        h0r, nullptr, w, l);
    __syncthreads();
    gru_layer<4, 9, 1, 40, true, true>(aT, aR1, aU1, nullptr,
                                       (const f16*)(smem + 36864), bgE1, bcE1,
                                       h1r, y1g + ((size_t)b * T_ + t) * 8192,
                                       w, l);
    __syncthreads();
  }

  // ================= switch to decoder =================
  {  // hd0 init = h1 final (same 4-tile layout); hd1 init = h0 final (2-tile)
    const int m16 = l & 15, kb4 = (l >> 4) << 2;
    const int cr4 = w & 3, ft04 = (w >> 2) * 4;
    const int co4 = cr4 * 16 + kb4;
#pragma unroll
    for (int j = 0; j < 4; ++j) {
      const int row = (ft04 + j) * 16 + m16 + 1;
      const int col = 64 + co4;
      f16x4 hh;
#pragma unroll
      for (int q = 0; q < 4; ++q) hh[q] = (f16)h1r[j][q];
      *(f16x4*)&aT[((col >> 3) * ROWSP + row) * 8 + (col & 7)] = hh;
    }
    const int cr2 = w & 1, ft02 = (w >> 1) * 2;
    const int co2 = cr2 * 16 + kb4;
#pragma unroll
    for (int j = 0; j < 2; ++j) {
      const int row = (ft02 + j) * 16 + m16 + 1;
      const int col = 128 + co2;
      f16x4 hh;
#pragma unroll
      for (int q = 0; q < 4; ++q) hh[q] = (f16)h0r[j][q];
      *(f16x4*)&aT[((col >> 3) * ROWSP + row) * 8 + (col & 7)] = hh;
    }
  }
  // load decoder LDS weights (enc reads finished at loop-end barrier)
  for (int i = tid; i < 3072; i += 512)
    ((f16x8*)(smem + 0))[i] = ((const f16x8*)wcD0)[i];
  for (int i = tid; i < 2304; i += 512)
    ((f16x8*)(smem + 49152))[i] = ((const f16x8*)wgD1)[i];
  for (int i = tid; i < 1152; i += 512)
    ((f16x8*)(smem + 86016))[i] = ((const f16x8*)wcD1)[i];
  // d0 gate weights -> VGPRs
  f16x8 aR0[12], aU0[12];
  {
    const int cr = w & 3;
#pragma unroll
    for (int ks = 0; ks < 12; ++ks) {
      aR0[ks] = *(const f16x8*)&wgD0[((cr * 12 + ks) * 64 + l) * 8];
      aU0[ks] = *(const f16x8*)&wgD0[(((cr + 4) * 12 + ks) * 64 + l) * 8];
    }
  }
  f32x4 hd0r[4], hd1r[2];
#pragma unroll
  for (int j = 0; j < 4; ++j) hd0r[j] = h1r[j];
#pragma unroll
  for (int j = 0; j < 2; ++j) hd1r[j] = h0r[j];
  __syncthreads();

  // ================= decoder =================
  for (int t = 0; t < T_; ++t) {
    {  // ingest y1(t) -> cols 0..63
      const f16x8* src = (const f16x8*)(y1g + ((size_t)b * T_ + t) * 8192);
#pragma unroll
      for (int k2 = 0; k2 < 2; ++k2) {
        const int i = tid + k2 * 512;
        const int cb = i >> 7, f = i & 127;
        *(f16x8*)&aT[(cb * ROWSP + f + 1) * 8] = src[i];
      }
    }
    __syncthreads();
    gru_layer<4, 12, 0, 64, true, false>(aT, aR0, aU0, nullptr,
                                         (const f16*)smem, bgD0, bcD0, hd0r,
                                         nullptr, w, l);
    __syncthreads();
    gru_layer<2, 9, 8, 128, false, false>(aT, nullptr, nullptr,
                                          (const f16*)(smem + 49152),
                                          (const f16*)(smem + 86016), bgD1,
                                          bcD1, hd1r, nullptr, w, l);
    __syncthreads();
    if (tid < F_) {  // final 1x1 conv (reads hd1 cols 128-159)
      float s = fb[0];
#pragma unroll
      for (int cb = 0; cb < 4; ++cb) {
        const f16x8 h8 = *(const f16x8*)&aT[((16 + cb) * ROWSP + tid + 1) * 8];
#pragma unroll
        for (int q = 0; q < 8; ++q) s = fmaf(fw[cb * 8 + q], (float)h8[q], s);
      }
      out[((size_t)b * T_ + t) * F_ + tid] = s;
    }
  }
}

// (CO,CI,3,3) fp32 -> f16 packed per MFMA A-fragment:
// dst[((cot*NK+ks)*64+lane)*8+j] = W[cot*16+(lane&15)][kk=ks*32+(lane>>4)*8+j],
// kk = k*CINH + c; c -> ci via identity (c<CI) or e0 map (x@0, h@8..39).
__global__ void repack_f16(const float* __restrict__ src, f16* __restrict__ dst,
                           int CO, int CI, int CINH, int NK, int e0map) {
  const int n = (CO / 16) * NK * 64;
  for (int i = blockIdx.x * blockDim.x + threadIdx.x; i < n;
       i += gridDim.x * blockDim.x) {
    const int cot = i / (NK * 64);
    const int r = i - cot * NK * 64;
    const int ks = r >> 6, lph = r & 63;
    const int co = cot * 16 + (lph & 15);
    const int kb = lph >> 4;
#pragma unroll
    for (int j = 0; j < 8; ++j) {
      const int kk = ks * 32 + kb * 8 + j;
      const int k = kk / CINH, c = kk - k * CINH;
      int ci;
      if (e0map) ci = (c == 0) ? 0 : ((c >= 8 && c < 40) ? c - 7 : -1);
      else ci = (c < CI) ? c : -1;
      float wv = 0.f;
      if (ci >= 0) wv = src[((size_t)(co * CI + ci) * 3 + k) * 3 + 1];
      dst[(size_t)i * 8 + j] = (f16)wv;
    }
  }
}

extern "C" void kernel_launch(void* const* d_in, const int* in_sizes, int n_in,
                              void* d_out, int out_size, void* d_ws, size_t ws_size,
                              hipStream_t stream) {
  (void)in_sizes; (void)n_in; (void)out_size; (void)ws_size;
  const float* x = (const float*)d_in[0];
  const float* e0_wg = (const float*)d_in[1];
  const float* e0_bg = (const float*)d_in[2];
  const float* e0_wc = (const float*)d_in[3];
  const float* e0_bc = (const float*)d_in[4];
  const float* e1_wg = (const float*)d_in[5];
  const float* e1_bg = (const float*)d_in[6];
  const float* e1_wc = (const float*)d_in[7];
  const float* e1_bc = (const float*)d_in[8];
  const float* d0_wg = (const float*)d_in[9];
  const float* d0_bg = (const float*)d_in[10];
  const float* d0_wc = (const float*)d_in[11];
  const float* d0_bc = (const float*)d_in[12];
  const float* d1_wg = (const float*)d_in[13];
  const float* d1_bg = (const float*)d_in[14];
  const float* d1_wc = (const float*)d_in[15];
  const float* d1_bc = (const float*)d_in[16];
  const float* fw = (const float*)d_in[17];
  const float* fb = (const float*)d_in[18];
  float* out = (float*)d_out;

  char* p = (char*)d_ws;
  f16* y1g = (f16*)p;
  p += (size_t)B_ * T_ * 64 * 128 * 2;  // 104.86 MB
  auto aw = [&](int n) { f16* q = (f16*)p; p += (size_t)n * 2; return q; };
  f16* wgE0 = aw(64 * 192);   // 12288 f16
  f16* wcE0 = aw(32 * 192);   //  6144
  f16* wgE1 = aw(128 * 288);  // 36864
  f16* wcE1 = aw(64 * 288);   // 18432
  f16* wgD0 = aw(128 * 384);  // 49152
  f16* wcD0 = aw(64 * 384);   // 24576
  f16* wgD1 = aw(64 * 288);   // 18432
  f16* wcD1 = aw(32 * 288);   //  9216

  auto rp = [&](const float* s, f16* d, int CO, int CI, int CINH, int e0m) {
    const int NK = 3 * CINH / 32;
    const int n = (CO / 16) * NK * 64;
    hipLaunchKernelGGL(repack_f16, dim3((n + 255) / 256), dim3(256), 0, stream,
                       s, d, CO, CI, CINH, NK, e0m);
  };
  rp(e0_wg, wgE0, 64, 33, 64, 1);
  rp(e0_wc, wcE0, 32, 33, 64, 1);
  rp(e1_wg, wgE1, 128, 96, 96, 0);
  rp(e1_wc, wcE1, 64, 96, 96, 0);
  rp(d0_wg, wgD0, 128, 128, 128, 0);
  rp(d0_wc, wcD0, 64, 128, 128, 0);
  rp(d1_wg, wgD1, 64, 96, 96, 0);
  rp(d1_wc, wcD1, 32, 96, 96, 0);

  const int lds = AT_OFF + 20 * ROWSP * 16;  // 104448 + 41600 = 146048
  hipFuncSetAttribute((const void*)ae_kernel,
                      hipFuncAttributeMaxDynamicSharedMemorySize, lds);
  hipLaunchKernelGGL(ae_kernel, dim3(B_), dim3(512), lds, stream, x, out,
                     wgE0, wcE0, e0_bg, e0_bc, wgE1, wcE1, e1_bg, e1_bc,
                     wgD0, wcD0, d0_bg, d0_bc, wgD1, wcD1, d1_bg, d1_bc,
                     fw, fb, y1g);
}

// Round 7
// 1272.385 us; speedup vs baseline: 46.2706x; 1.2770x over previous
//
#include <hip/hip_runtime.h>
#include <cstdint>
#include <cstddef>

// ConvGRU autoencoder, round 7: single block per batch, 4 layers in-block.
// vs round 6: (a) rh in separate LDS cols (+x-dup col) -> 5 barriers/t (was 9);
// (b) one-base + immediate-offset LDS addressing (all cb indices affine in kb);
// (c) biases preloaded in VGPRs with exp2 scales folded (no per-t global bias
// loads, fma+exp2+add+rcp per gate); (d) x pre-converted to f16.
//
// aT layout (cb = 8 cols, 130 rows x 8 f16):
//  enc: cb0 x(+pad), cb1-4 h0, cb5-12 h1, cb13 x-dup(+pad), cb14-17 rh0,
//       cb18-25 rh1
//  dec: cb0-7 y1, cb8-15 hd0, cb16-19 hd1, cb20-27 rh (d0: 20-27, d1: 20-23)
// Weights LDS: enc wgE0@0 wcE0@24576 wcE1@36864 (73.7KB);
//              dec wcD0@0 wgD1@49152 wcD1@86016 (104.4KB). aT @104448.

#define F_ 128
#define T_ 100
#define B_ 64
#define ROWSP 130
#define CBSTR (ROWSP * 8)    // f16 per cb
#define CBBYTE (ROWSP * 16)  // 2080 bytes per cb
#define AT_OFF 104448
#define LDS_TOTAL (AT_OFF + 28 * CBBYTE)  // 162688

typedef _Float16 f16;
typedef __attribute__((ext_vector_type(4))) float f32x4;
typedef __attribute__((ext_vector_type(8))) _Float16 f16x8;
typedef __attribute__((ext_vector_type(4))) _Float16 f16x4;

#define MFMA(a, b, c) __builtin_amdgcn_mfma_f32_16x16x32_f16(a, b, c, 0, 0, 0)

__device__ __forceinline__ float exp2_(float x) { return __builtin_amdgcn_exp2f(x); }
__device__ __forceinline__ float rcp_(float x) { return __builtin_amdgcn_rcpf(x); }

#define KSG (-1.442695041f)  // sigmoid: sig(v) = rcp(1+exp2(v*KSG))
#define KTH (-2.885390082f)  // tanh:    tanh(v) = 2*rcp(1+exp2(v*KTH)) - 1

// cb base per (layer, ks%NC3); fragment cb = base + kb (kb = lane>>4).
__host__ __device__ constexpr int cbA(int lid, int km) {
  return lid == 0 ? (km ? 4 : 0)
       : lid == 1 ? (1 + km * 4)
       : lid == 2 ? (km * 4)
                  : (8 + km * 4);
}
__host__ __device__ constexpr int cbB(int lid, int km) {
  return lid == 0 ? (km ? 17 : 13)
       : lid == 1 ? (km == 0 ? 1 : 14 + km * 4)
       : lid == 2 ? (km < 2 ? km * 4 : 12 + km * 4)
                  : (km < 2 ? 8 + km * 4 : 20);
}

// One GRU layer step. rdB/wrB: per-thread LDS bases (all offsets compile-time).
// hreg: per-thread fp32 master state (FTW x f32x4). One internal barrier.
// Caller barriers before (inputs ready) and after (h visible).
template <int LID, int NCR, int NK, int NC3, int HC, int RHC, bool GREG, bool EMITY1>
__device__ __forceinline__ void gru_layer(
    const f16* __restrict__ rdB, char* __restrict__ wrB,
    const f16x8* __restrict__ aR, const f16x8* __restrict__ aU,
    const f16* __restrict__ gR, const f16* __restrict__ gU,
    const f16* __restrict__ cW, const f32x4 bR2, const f32x4 bU2,
    const f32x4 bC2, f32x4* __restrict__ hreg, f16* __restrict__ y1dst) {
  constexpr int FTW = NCR;
  // ---- conv A: R,U gates over [x ; h] ----
  f32x4 accR[FTW], accU[FTW];
#pragma unroll
  for (int j = 0; j < FTW; ++j) {
    accR[j] = (f32x4){0.f, 0.f, 0.f, 0.f};
    accU[j] = (f32x4){0.f, 0.f, 0.f, 0.f};
  }
#pragma unroll
  for (int ks = 0; ks < NK; ++ks) {
    const int k = ks / NC3, km = ks % NC3;
    const f16* fb = rdB + cbA(LID, km) * CBSTR + k * 8;
    f16x8 bf[FTW];
#pragma unroll
    for (int j = 0; j < FTW; ++j) bf[j] = *(const f16x8*)(fb + j * 128);
    f16x8 wr, wu;
    if constexpr (GREG) {
      wr = aR[ks];
      wu = aU[ks];
    } else {
      wr = *(const f16x8*)(gR + ks * 512);
      wu = *(const f16x8*)(gU + ks * 512);
    }
#pragma unroll
    for (int j = 0; j < FTW; ++j) accR[j] = MFMA(wr, bf[j], accR[j]);
#pragma unroll
    for (int j = 0; j < FTW; ++j) accU[j] = MFMA(wu, bf[j], accU[j]);
  }
  // ---- post A: rh = sigm(R)*h into rh cols (u deferred to post B) ----
#pragma unroll
  for (int j = 0; j < FTW; ++j) {
    f16x4 rh;
#pragma unroll
    for (int q = 0; q < 4; ++q) {
      const float r = rcp_(1.0f + exp2_(fmaf(accR[j][q], KSG, bR2[q])));
      rh[q] = (f16)(r * hreg[j][q]);
    }
    *(f16x4*)(wrB + (RHC >> 3) * CBBYTE + j * 256) = rh;
  }
  __syncthreads();  // rh visible to all waves
  // ---- conv B: candidate over [x ; r*h] ----
  f32x4 accC[FTW];
#pragma unroll
  for (int j = 0; j < FTW; ++j) accC[j] = (f32x4){0.f, 0.f, 0.f, 0.f};
#pragma unroll
  for (int ks = 0; ks < NK; ++ks) {
    const int k = ks / NC3, km = ks % NC3;
    const f16* fb = rdB + cbB(LID, km) * CBSTR + k * 8;
    f16x8 bf[FTW];
#pragma unroll
    for (int j = 0; j < FTW; ++j) bf[j] = *(const f16x8*)(fb + j * 128);
    const f16x8 wc = *(const f16x8*)(cW + ks * 512);
#pragma unroll
    for (int j = 0; j < FTW; ++j) accC[j] = MFMA(wc, bf[j], accC[j]);
  }
  // ---- post B: u = sigm(U); h = h + u*(tanh(C) - h); write h cols ----
#pragma unroll
  for (int j = 0; j < FTW; ++j) {
    f16x4 hh;
#pragma unroll
    for (int q = 0; q < 4; ++q) {
      const float u = rcp_(1.0f + exp2_(fmaf(accU[j][q], KSG, bU2[q])));
      const float r = rcp_(1.0f + exp2_(fmaf(accC[j][q], KTH, bC2[q])));
      const float h = hreg[j][q];
      const float s = fmaf(2.0f, r, -(1.0f + h));  // tanh(C) - h
      const float hn = fmaf(u, s, h);
      hreg[j][q] = hn;
      hh[q] = (f16)hn;
    }
    *(f16x4*)(wrB + (HC >> 3) * CBBYTE + j * 256) = hh;
    if constexpr (EMITY1) *(f16x4*)(y1dst + j * 128) = hh;
  }
}

__global__ __launch_bounds__(512, 2) void ae_kernel(
    const f16* __restrict__ xf, float* __restrict__ out,
    const f16* __restrict__ wgE0, const f16* __restrict__ wcE0,
    const float* __restrict__ bgE0, const float* __restrict__ bcE0,
    const f16* __restrict__ wgE1, const f16* __restrict__ wcE1,
    const float* __restrict__ bgE1, const float* __restrict__ bcE1,
    const f16* __restrict__ wgD0, const f16* __restrict__ wcD0,
    const float* __restrict__ bgD0, const float* __restrict__ bcD0,
    const f16* __restrict__ wgD1, const f16* __restrict__ wcD1,
    const float* __restrict__ bgD1, const float* __restrict__ bcD1,
    const float* __restrict__ fw, const float* __restrict__ fb,
    f16* __restrict__ y1g) {
  extern __shared__ char smem[];
  f16* aT = (f16*)(smem + AT_OFF);
  const int tid = threadIdx.x, b = blockIdx.x;
  const int w = tid >> 6, l = tid & 63;
  const int m16 = l & 15, kb = l >> 4;

  // zero aT (28 cb)
  for (int i = tid; i < 28 * CBBYTE / 16; i += 512)
    ((f32x4*)(smem + AT_OFF))[i] = (f32x4){0.f, 0.f, 0.f, 0.f};
  // encoder weights -> LDS
  for (int i = tid; i < 1536; i += 512)
    ((f16x8*)(smem + 0))[i] = ((const f16x8*)wgE0)[i];
  for (int i = tid; i < 768; i += 512)
    ((f16x8*)(smem + 24576))[i] = ((const f16x8*)wcE0)[i];
  for (int i = tid; i < 2304; i += 512)
    ((f16x8*)(smem + 36864))[i] = ((const f16x8*)wcE1)[i];

  // e1 gate weights -> VGPRs
  const int cot2 = w & 1, cot4 = w & 3;
  f16x8 aR1[9], aU1[9];
#pragma unroll
  for (int ks = 0; ks < 9; ++ks) {
    aR1[ks] = ((const f16x8*)wgE1)[(cot4 * 9 + ks) * 64 + l];
    aU1[ks] = ((const f16x8*)wgE1)[((cot4 + 4) * 9 + ks) * 64 + l];
  }
  // bias preload (scale folded)
  const int co2 = cot2 * 16 + kb * 4;
  const int co4 = cot4 * 16 + kb * 4;
  f32x4 bRe0, bUe0, bCe0, bRe1, bUe1, bCe1;
#pragma unroll
  for (int q = 0; q < 4; ++q) {
    bRe0[q] = bgE0[co2 + q] * KSG;
    bUe0[q] = bgE0[32 + co2 + q] * KSG;
    bCe0[q] = bcE0[co2 + q] * KTH;
    bRe1[q] = bgE1[co4 + q] * KSG;
    bUe1[q] = bgE1[64 + co4 + q] * KSG;
    bCe1[q] = bcE1[co4 + q] * KTH;
  }
  // per-thread LDS bases (2-tile and 4-tile variants)
  const int ft2 = (w >> 1) * 2, ft4 = (w >> 2) * 4;
  const f16* rdB2 = aT + kb * CBSTR + (ft2 * 16 + m16) * 8;
  const f16* rdB4 = aT + kb * CBSTR + (ft4 * 16 + m16) * 8;
  char* wrB2 = (char*)aT + (cot2 * 2 + (kb >> 1)) * CBBYTE +
               (ft2 * 16 + m16 + 1) * 16 + (kb & 1) * 8;
  char* wrB4 = (char*)aT + (cot4 * 2 + (kb >> 1)) * CBBYTE +
               (ft4 * 16 + m16 + 1) * 16 + (kb & 1) * 8;
  f16* y1t = y1g + (size_t)b * T_ * 8192 +
             ((cot4 * 2 + (kb >> 1)) * 128 + ft4 * 16 + m16) * 8 + (kb & 1) * 4;
  // LDS weight pointers (per-thread base + ks*512 immediate)
  const f16* gE0R = (const f16*)(smem + 0) + (cot2 * 6 * 64 + l) * 8;
  const f16* gE0U = (const f16*)(smem + 0) + ((cot2 + 2) * 6 * 64 + l) * 8;
  const f16* cE0 = (const f16*)(smem + 24576) + (cot2 * 6 * 64 + l) * 8;
  const f16* cE1 = (const f16*)(smem + 36864) + (cot4 * 9 * 64 + l) * 8;

  f32x4 h0r[2], h1r[4];
#pragma unroll
  for (int j = 0; j < 2; ++j) h0r[j] = (f32x4){0.f, 0.f, 0.f, 0.f};
#pragma unroll
  for (int j = 0; j < 4; ++j) h1r[j] = (f32x4){0.f, 0.f, 0.f, 0.f};
  __syncthreads();

  // ================= encoder =================
  const f16* xb = xf + (size_t)b * T_ * F_;
  for (int t = 0; t < T_; ++t) {
    if (tid < F_) {  // x into col 0 and dup col 104 (cb13)
      const f16 v = xb[t * F_ + tid];
      aT[(tid + 1) * 8] = v;
      aT[13 * CBSTR + (tid + 1) * 8] = v;
    }
    __syncthreads();
    gru_layer<0, 2, 6, 2, 8, 112, false, false>(
        rdB2, wrB2, nullptr, nullptr, gE0R, gE0U, cE0, bRe0, bUe0, bCe0, h0r,
        nullptr);
    __syncthreads();
    gru_layer<1, 4, 9, 3, 40, 144, true, true>(
        rdB4, wrB4, aR1, aU1, nullptr, nullptr, cE1, bRe1, bUe1, bCe1, h1r,
        y1t + t * 8192);
    __syncthreads();
  }

  // ================= switch to decoder =================
  {  // hd0 init cols 64+ (from h1r, e1 tiling); hd1 init cols 128+ (h0r)
#pragma unroll
    for (int j = 0; j < 4; ++j) {
      f16x4 hh;
#pragma unroll
      for (int q = 0; q < 4; ++q) hh[q] = (f16)h1r[j][q];
      *(f16x4*)(wrB4 + 8 * CBBYTE + j * 256) = hh;
    }
#pragma unroll
    for (int j = 0; j < 2; ++j) {
      f16x4 hh;
#pragma unroll
      for (int q = 0; q < 4; ++q) hh[q] = (f16)h0r[j][q];
      *(f16x4*)(wrB2 + 16 * CBBYTE + j * 256) = hh;
    }
  }
  // decoder weights -> LDS (enc weight reads all done at loop-end barrier)
  for (int i = tid; i < 3072; i += 512)
    ((f16x8*)(smem + 0))[i] = ((const f16x8*)wcD0)[i];
  for (int i = tid; i < 2304; i += 512)
    ((f16x8*)(smem + 49152))[i] = ((const f16x8*)wgD1)[i];
  for (int i = tid; i < 1152; i += 512)
    ((f16x8*)(smem + 86016))[i] = ((const f16x8*)wcD1)[i];
  // d0 gate weights -> VGPRs
  f16x8 aR0[12], aU0[12];
#pragma unroll
  for (int ks = 0; ks < 12; ++ks) {
    aR0[ks] = ((const f16x8*)wgD0)[(cot4 * 12 + ks) * 64 + l];
    aU0[ks] = ((const f16x8*)wgD0)[((cot4 + 4) * 12 + ks) * 64 + l];
  }
  f32x4 bRd0, bUd0, bCd0, bRd1, bUd1, bCd1;
#pragma unroll
  for (int q = 0; q < 4; ++q) {
    bRd0[q] = bgD0[co4 + q] * KSG;
    bUd0[q] = bgD0[64 + co4 + q] * KSG;
    bCd0[q] = bcD0[co4 + q] * KTH;
    bRd1[q] = bgD1[co2 + q] * KSG;
    bUd1[q] = bgD1[32 + co2 + q] * KSG;
    bCd1[q] = bcD1[co2 + q] * KTH;
  }
  const f16* gD1R = (const f16*)(smem + 49152) + (cot2 * 9 * 64 + l) * 8;
  const f16* gD1U = (const f16*)(smem + 49152) + ((cot2 + 2) * 9 * 64 + l) * 8;
  const f16* cD0 = (const f16*)(smem + 0) + (cot4 * 12 * 64 + l) * 8;
  const f16* cD1 = (const f16*)(smem + 86016) + (cot2 * 9 * 64 + l) * 8;
  __syncthreads();

  // ================= decoder =================
  for (int t = 0; t < T_; ++t) {
    {  // ingest y1(t) -> cb0-7
      const f16x8* src = (const f16x8*)(y1g + ((size_t)b * T_ + t) * 8192);
#pragma unroll
      for (int k2 = 0; k2 < 2; ++k2) {
        const int i = tid + k2 * 512;
        *(f16x8*)&aT[(i >> 7) * CBSTR + ((i & 127) + 1) * 8] = src[i];
      }
    }
    __syncthreads();
    gru_layer<2, 4, 12, 4, 64, 160, true, false>(
        rdB4, wrB4, aR0, aU0, nullptr, nullptr, cD0, bRd0, bUd0, bCd0, h1r,
        nullptr);
    __syncthreads();
    gru_layer<3, 2, 9, 3, 128, 160, false, false>(
        rdB2, wrB2, nullptr, nullptr, gD1R, gD1U, cD1, bRd1, bUd1, bCd1, h0r,
        nullptr);
    __syncthreads();
    if (tid < F_) {  // final 1x1 conv over hd1 (cb16-19)
      float s = fb[0];
#pragma unroll
      for (int cb = 0; cb < 4; ++cb) {
        const f16x8 h8 = *(const f16x8*)&aT[(16 + cb) * CBSTR + (tid + 1) * 8];
#pragma unroll
        for (int q = 0; q < 8; ++q) s = fmaf(fw[cb * 8 + q], (float)h8[q], s);
      }
      out[((size_t)b * T_ + t) * F_ + tid] = s;
    }
  }
}

// (CO,CI,3,3) fp32 -> f16 packed per MFMA A-fragment (same as round 6).
__global__ void repack_f16(const float* __restrict__ src, f16* __restrict__ dst,
                           int CO, int CI, int CINH, int NK, int e0map) {
  const int n = (CO / 16) * NK * 64;
  for (int i = blockIdx.x * blockDim.x + threadIdx.x; i < n;
       i += gridDim.x * blockDim.x) {
    const int cot = i / (NK * 64);
    const int r = i - cot * NK * 64;
    const int ks = r >> 6, lph = r & 63;
    const int co = cot * 16 + (lph & 15);
    const int kbl = lph >> 4;
#pragma unroll
    for (int j = 0; j < 8; ++j) {
      const int kk = ks * 32 + kbl * 8 + j;
      const int k = kk / CINH, c = kk - k * CINH;
      int ci;
      if (e0map) ci = (c == 0) ? 0 : ((c >= 8 && c < 40) ? c - 7 : -1);
      else ci = (c < CI) ? c : -1;
      float wv = 0.f;
      if (ci >= 0) wv = src[((size_t)(co * CI + ci) * 3 + k) * 3 + 1];
      dst[(size_t)i * 8 + j] = (f16)wv;
    }
  }
}

__global__ void xcvt(const float* __restrict__ x, f16* __restrict__ xf, int n4) {
  for (int i = blockIdx.x * blockDim.x + threadIdx.x; i < n4;
       i += gridDim.x * blockDim.x) {
    const float4 v = ((const float4*)x)[i];
    f16x4 o;
    o[0] = (f16)v.x; o[1] = (f16)v.y; o[2] = (f16)v.z; o[3] = (f16)v.w;
    ((f16x4*)xf)[i] = o;
  }
}

extern "C" void kernel_launch(void* const* d_in, const int* in_sizes, int n_in,
                              void* d_out, int out_size, void* d_ws, size_t ws_size,
                              hipStream_t stream) {
  (void)in_sizes; (void)n_in; (void)out_size; (void)ws_size;
  const float* x = (const float*)d_in[0];
  const float* e0_wg = (const float*)d_in[1];
  const float* e0_bg = (const float*)d_in[2];
  const float* e0_wc = (const float*)d_in[3];
  const float* e0_bc = (const float*)d_in[4];
  const float* e1_wg = (const float*)d_in[5];
  const float* e1_bg = (const float*)d_in[6];
  const float* e1_wc = (const float*)d_in[7];
  const float* e1_bc = (const float*)d_in[8];
  const float* d0_wg = (const float*)d_in[9];
  const float* d0_bg = (const float*)d_in[10];
  const float* d0_wc = (const float*)d_in[11];
  const float* d0_bc = (const float*)d_in[12];
  const float* d1_wg = (const float*)d_in[13];
  const float* d1_bg = (const float*)d_in[14];
  const float* d1_wc = (const float*)d_in[15];
  const float* d1_bc = (const float*)d_in[16];
  const float* fw = (const float*)d_in[17];
  const float* fb = (const float*)d_in[18];
  float* out = (float*)d_out;

  char* p = (char*)d_ws;
  f16* y1g = (f16*)p;
  p += (size_t)B_ * T_ * 64 * 128 * 2;  // 104.86 MB
  f16* xf = (f16*)p;
  p += (size_t)B_ * T_ * F_ * 2;        // 1.64 MB
  auto aw = [&](int n) { f16* q = (f16*)p; p += (size_t)n * 2; return q; };
  f16* wgE0 = aw(64 * 192);
  f16* wcE0 = aw(32 * 192);
  f16* wgE1 = aw(128 * 288);
  f16* wcE1 = aw(64 * 288);
  f16* wgD0 = aw(128 * 384);
  f16* wcD0 = aw(64 * 384);
  f16* wgD1 = aw(64 * 288);
  f16* wcD1 = aw(32 * 288);

  auto rp = [&](const float* s, f16* d, int CO, int CI, int CINH, int e0m) {
    const int NK = 3 * CINH / 32;
    const int n = (CO / 16) * NK * 64;
    hipLaunchKernelGGL(repack_f16, dim3((n + 255) / 256), dim3(256), 0, stream,
                       s, d, CO, CI, CINH, NK, e0m);
  };
  rp(e0_wg, wgE0, 64, 33, 64, 1);
  rp(e0_wc, wcE0, 32, 33, 64, 1);
  rp(e1_wg, wgE1, 128, 96, 96, 0);
  rp(e1_wc, wcE1, 64, 96, 96, 0);
  rp(d0_wg, wgD0, 128, 128, 128, 0);
  rp(d0_wc, wcD0, 64, 128, 128, 0);
  rp(d1_wg, wgD1, 64, 96, 96, 0);
  rp(d1_wc, wcD1, 32, 96, 96, 0);
  hipLaunchKernelGGL(xcvt, dim3(200), dim3(1024), 0, stream, x, xf,
                     B_ * T_ * F_ / 4);

  hipFuncSetAttribute((const void*)ae_kernel,
                      hipFuncAttributeMaxDynamicSharedMemorySize, LDS_TOTAL);
  hipLaunchKernelGGL(ae_kernel, dim3(B_), dim3(512), LDS_TOTAL, stream, xf, out,
                     wgE0, wcE0, e0_bg, e0_bc, wgE1, wcE1, e1_bg, e1_bc,
                     wgD0, wcD0, d0_bg, d0_bc, wgD1, wcD1, d1_bg, d1_bc,
                     fw, fb, y1g);
}